// Round 1
// baseline (8488.509 us; speedup 1.0000x reference)
//
#include <hip/hip_runtime.h>
#include <math.h>

#define NN 100000      // nodes
#define NE 1600000     // edges
#define IN_DIM 6
#define EDGE_DIM 2
#define HH 5           // heads
#define CC 5           // channels/head
#define DD 25          // hidden = HH*CC
#define DS 32          // padded row stride for h/q/k/v (128B-aligned rows)
#define INV_SQRT_C 0.4472135954999579f

__device__ __forceinline__ void atomicMaxFloat(float* addr, float val) {
    // standard two-branch int trick; addr initialized to -inf (0xFF800000)
    if (val >= 0.0f) atomicMax((int*)addr, __float_as_int(val));
    else             atomicMin((unsigned int*)addr, __float_as_uint(val));
}

// ---------------- input projection: h = x @ Wi + bi ----------------
__global__ void k_input_proj(const float* __restrict__ x, const float* __restrict__ Wi,
                             const float* __restrict__ bi, float* __restrict__ h) {
    __shared__ float sW[IN_DIM * DD];
    __shared__ float sb[DD];
    int t = threadIdx.x;
    if (t < IN_DIM * DD) sW[t] = Wi[t];
    if (t < DD) sb[t] = bi[t];
    __syncthreads();
    int tid = blockIdx.x * blockDim.x + t;
    int n = tid / DD, d = tid - n * DD;
    if (n >= NN) return;
    float acc = sb[d];
    const float* xr = x + n * IN_DIM;
#pragma unroll
    for (int i = 0; i < IN_DIM; i++) acc += xr[i] * sW[i * DD + d];
    h[n * DS + d] = acc;
}

// ------- per-layer node pass: q,k,v = h@W*, hout = h@Wskip+bskip; init amax/denom -------
__global__ void k_qkv_skip(const float* __restrict__ h,
                           const float* __restrict__ Wq, const float* __restrict__ bq,
                           const float* __restrict__ Wk, const float* __restrict__ bk,
                           const float* __restrict__ Wv, const float* __restrict__ bv,
                           const float* __restrict__ Ws, const float* __restrict__ bs,
                           float* __restrict__ q, float* __restrict__ k, float* __restrict__ v,
                           float* __restrict__ hout, float* __restrict__ amax,
                           float* __restrict__ denom) {
    __shared__ float sWq[DD * DD], sWk[DD * DD], sWv[DD * DD], sWs[DD * DD];
    __shared__ float sb[4 * DD];
    for (int i = threadIdx.x; i < DD * DD; i += blockDim.x) {
        sWq[i] = Wq[i]; sWk[i] = Wk[i]; sWv[i] = Wv[i]; sWs[i] = Ws[i];
    }
    if (threadIdx.x < DD) {
        sb[threadIdx.x]          = bq[threadIdx.x];
        sb[DD + threadIdx.x]     = bk[threadIdx.x];
        sb[2 * DD + threadIdx.x] = bv[threadIdx.x];
        sb[3 * DD + threadIdx.x] = bs[threadIdx.x];
    }
    __syncthreads();
    int tid = blockIdx.x * blockDim.x + threadIdx.x;
    int n = tid / DD, d = tid - n * DD;
    if (n >= NN) return;
    float aq = sb[d], ak = sb[DD + d], av = sb[2 * DD + d], asv = sb[3 * DD + d];
    const float* hr = h + n * DS;
#pragma unroll
    for (int i = 0; i < DD; i++) {
        float hv = hr[i];
        aq  += hv * sWq[i * DD + d];
        ak  += hv * sWk[i * DD + d];
        av  += hv * sWv[i * DD + d];
        asv += hv * sWs[i * DD + d];
    }
    q[n * DS + d] = aq;
    k[n * DS + d] = ak;
    v[n * DS + d] = av;
    hout[n * DS + d] = asv;
    if (d < HH) {
        amax[n * HH + d] = -INFINITY;
        denom[n * HH + d] = 0.0f;
    }
}

// ------- edge pass A: alpha_raw = (q[dst] . (k[src]+e)) / sqrt(C); atomic max -------
__global__ void k_edge_alpha(const int* __restrict__ ei, const float* __restrict__ ea,
                             const float* __restrict__ We,
                             const float* __restrict__ q, const float* __restrict__ k,
                             float* __restrict__ alpha, float* __restrict__ amax) {
    __shared__ float sWe[EDGE_DIM * DD];
    if (threadIdx.x < EDGE_DIM * DD) sWe[threadIdx.x] = We[threadIdx.x];
    __syncthreads();
    int e = blockIdx.x * blockDim.x + threadIdx.x;
    if (e >= NE) return;
    int src = ei[e], dst = ei[NE + e];
    float2 eav = ((const float2*)ea)[e];
    const float4* qr = (const float4*)(q + (size_t)dst * DS);
    const float4* kr = (const float4*)(k + (size_t)src * DS);
    float qa[28], ka[28];
#pragma unroll
    for (int i = 0; i < 7; i++) {
        float4 tq = qr[i];
        qa[4*i] = tq.x; qa[4*i+1] = tq.y; qa[4*i+2] = tq.z; qa[4*i+3] = tq.w;
        float4 tk = kr[i];
        ka[4*i] = tk.x; ka[4*i+1] = tk.y; ka[4*i+2] = tk.z; ka[4*i+3] = tk.w;
    }
#pragma unroll
    for (int hd = 0; hd < HH; hd++) {
        float a = 0.0f;
#pragma unroll
        for (int c = 0; c < CC; c++) {
            int j = hd * CC + c;
            float ev = eav.x * sWe[j] + eav.y * sWe[DD + j];
            a += qa[j] * (ka[j] + ev);
        }
        a *= INV_SQRT_C;
        alpha[(size_t)e * HH + hd] = a;
        atomicMaxFloat(&amax[dst * HH + hd], a);
    }
}

// ------- edge pass B: ex = exp(alpha - amax[dst]); denom += ex -------
__global__ void k_edge_exp(const int* __restrict__ ei, const float* __restrict__ amax,
                           float* __restrict__ alpha, float* __restrict__ denom) {
    int e = blockIdx.x * blockDim.x + threadIdx.x;
    if (e >= NE) return;
    int dst = ei[NE + e];
#pragma unroll
    for (int hd = 0; hd < HH; hd++) {
        float ex = __expf(alpha[(size_t)e * HH + hd] - amax[dst * HH + hd]);
        alpha[(size_t)e * HH + hd] = ex;
        unsafeAtomicAdd(&denom[dst * HH + hd], ex);
    }
}

// ------- edge pass C: hout[dst] += (v[src]+e) * ex/denom[dst] -------
__global__ void k_edge_msg(const int* __restrict__ ei, const float* __restrict__ ea,
                           const float* __restrict__ We,
                           const float* __restrict__ v, const float* __restrict__ alpha,
                           const float* __restrict__ denom, float* __restrict__ hout) {
    __shared__ float sWe[EDGE_DIM * DD];
    if (threadIdx.x < EDGE_DIM * DD) sWe[threadIdx.x] = We[threadIdx.x];
    __syncthreads();
    int e = blockIdx.x * blockDim.x + threadIdx.x;
    if (e >= NE) return;
    int src = ei[e], dst = ei[NE + e];
    float2 eav = ((const float2*)ea)[e];
    const float4* vr = (const float4*)(v + (size_t)src * DS);
    float va[28];
#pragma unroll
    for (int i = 0; i < 7; i++) {
        float4 tv = vr[i];
        va[4*i] = tv.x; va[4*i+1] = tv.y; va[4*i+2] = tv.z; va[4*i+3] = tv.w;
    }
    float* ho = hout + (size_t)dst * DS;
#pragma unroll
    for (int hd = 0; hd < HH; hd++) {
        float a = alpha[(size_t)e * HH + hd] / (denom[dst * HH + hd] + 1e-16f);
#pragma unroll
        for (int c = 0; c < CC; c++) {
            int j = hd * CC + c;
            float ev = eav.x * sWe[j] + eav.y * sWe[DD + j];
            unsafeAtomicAdd(&ho[j], (va[j] + ev) * a);
        }
    }
}

// ------- output head: out = sigmoid(h @ Wo + bo) -------
__global__ void k_head(const float* __restrict__ h, const float* __restrict__ Wo,
                       const float* __restrict__ bo, float* __restrict__ out) {
    __shared__ float sW[DD];
    __shared__ float sb0;
    if (threadIdx.x < DD) sW[threadIdx.x] = Wo[threadIdx.x];
    if (threadIdx.x == 0) sb0 = bo[0];
    __syncthreads();
    int n = blockIdx.x * blockDim.x + threadIdx.x;
    if (n >= NN) return;
    float acc = sb0;
    const float* hr = h + (size_t)n * DS;
#pragma unroll
    for (int i = 0; i < DD; i++) acc += hr[i] * sW[i];
    out[n] = 1.0f / (1.0f + __expf(-acc));
}

extern "C" void kernel_launch(void* const* d_in, const int* in_sizes, int n_in,
                              void* d_out, int out_size, void* d_ws, size_t ws_size,
                              hipStream_t stream) {
    const float* x     = (const float*)d_in[0];
    const int*   ei    = (const int*)d_in[1];     // [2,E]: src = [0..E), dst = [E..2E)
    const float* ea    = (const float*)d_in[2];   // [E,2]
    const float* Wi    = (const float*)d_in[3];
    const float* bi    = (const float*)d_in[4];
    const float* Wq    = (const float*)d_in[5];
    const float* bq    = (const float*)d_in[6];
    const float* Wk    = (const float*)d_in[7];
    const float* bk    = (const float*)d_in[8];
    const float* Wv    = (const float*)d_in[9];
    const float* bv    = (const float*)d_in[10];
    const float* We    = (const float*)d_in[11];
    const float* Wskip = (const float*)d_in[12];
    const float* bskip = (const float*)d_in[13];
    const float* Wo    = (const float*)d_in[14];
    const float* bo    = (const float*)d_in[15];
    float* out = (float*)d_out;

    float* ws = (float*)d_ws;
    size_t off = 0;
    float* hA    = ws + off; off += (size_t)NN * DS;   // 3.2M
    float* hB    = ws + off; off += (size_t)NN * DS;
    float* q     = ws + off; off += (size_t)NN * DS;
    float* k     = ws + off; off += (size_t)NN * DS;
    float* v     = ws + off; off += (size_t)NN * DS;
    float* amax  = ws + off; off += (size_t)NN * HH;
    float* denom = ws + off; off += (size_t)NN * HH;
    float* alpha = ws + off; off += (size_t)NE * HH;   // 8M
    (void)ws_size; (void)in_sizes; (void)n_in; (void)out_size;

    dim3 blk(256);
    int gn = (NN * DD + 255) / 256;     // node*dim threads
    int ge = (NE + 255) / 256;          // edge threads (exactly 6250 blocks)
    int gh = (NN + 255) / 256;

    k_input_proj<<<gn, blk, 0, stream>>>(x, Wi, bi, hA);

    float* hc = hA;
    float* hn = hB;
    for (int l = 0; l < 3; l++) {
        k_qkv_skip<<<gn, blk, 0, stream>>>(hc,
                                           Wq + (size_t)l * DD * DD, bq + (size_t)l * DD,
                                           Wk + (size_t)l * DD * DD, bk + (size_t)l * DD,
                                           Wv + (size_t)l * DD * DD, bv + (size_t)l * DD,
                                           Wskip + (size_t)l * DD * DD, bskip + (size_t)l * DD,
                                           q, k, v, hn, amax, denom);
        k_edge_alpha<<<ge, blk, 0, stream>>>(ei, ea, We + (size_t)l * EDGE_DIM * DD,
                                             q, k, alpha, amax);
        k_edge_exp<<<ge, blk, 0, stream>>>(ei, amax, alpha, denom);
        k_edge_msg<<<ge, blk, 0, stream>>>(ei, ea, We + (size_t)l * EDGE_DIM * DD,
                                           v, alpha, denom, hn);
        float* t = hc; hc = hn; hn = t;
    }
    k_head<<<gh, blk, 0, stream>>>(hc, Wo, bo, out);
}

// Round 2
// 719.734 us; speedup vs baseline: 11.7940x; 11.7940x over previous
//
#include <hip/hip_runtime.h>
#include <math.h>

#define NN 100000      // nodes
#define NE 1600000     // edges
#define IN_DIM 6
#define EDGE_DIM 2
#define HH 5           // heads
#define CC 5           // channels/head
#define DD 25          // hidden = HH*CC
#define DS 32          // padded row stride (128B rows)
#define INV_SQRT_C 0.4472135954999579f
#define SCAN_B 256
#define NB1 ((NN + SCAN_B - 1) / SCAN_B)   // 391

// ---------------- CSR build ----------------
__global__ void k_zero_deg(int* __restrict__ deg) {
    int i = blockIdx.x * 256 + threadIdx.x;
    if (i < NN) deg[i] = 0;
}

__global__ void k_hist(const int* __restrict__ ei, int* __restrict__ deg) {
    int e = blockIdx.x * 256 + threadIdx.x;
    if (e < NE) atomicAdd(&deg[ei[NE + e]], 1);
}

__global__ void k_scan1(const int* __restrict__ deg, int* __restrict__ excl,
                        int* __restrict__ bsum) {
    __shared__ int s[SCAN_B];
    int i = blockIdx.x * SCAN_B + threadIdx.x;
    int v = (i < NN) ? deg[i] : 0;
    s[threadIdx.x] = v;
    __syncthreads();
    for (int off = 1; off < SCAN_B; off <<= 1) {
        int t = (threadIdx.x >= off) ? s[threadIdx.x - off] : 0;
        __syncthreads();
        s[threadIdx.x] += t;
        __syncthreads();
    }
    if (i < NN) excl[i] = s[threadIdx.x] - v;
    if (threadIdx.x == SCAN_B - 1) bsum[blockIdx.x] = s[SCAN_B - 1];
}

__global__ void k_scan2(int* __restrict__ bsum) {   // single block of 512
    __shared__ int s[512];
    int t = threadIdx.x;
    int v = (t < NB1) ? bsum[t] : 0;
    s[t] = v;
    __syncthreads();
    for (int off = 1; off < 512; off <<= 1) {
        int u = (t >= off) ? s[t - off] : 0;
        __syncthreads();
        s[t] += u;
        __syncthreads();
    }
    if (t < NB1) bsum[t] = s[t] - v;   // exclusive block offsets
}

__global__ void k_scan3(const int* __restrict__ excl, const int* __restrict__ bsum,
                        int* __restrict__ rowptr, int* __restrict__ cur) {
    int i = blockIdx.x * 256 + threadIdx.x;
    if (i < NN) {
        int r = excl[i] + bsum[i / SCAN_B];
        rowptr[i] = r;
        cur[i] = r;
    }
    if (i == 0) rowptr[NN] = NE;
}

__global__ void k_scatter(const int* __restrict__ ei, const float* __restrict__ ea,
                          int* __restrict__ cur, int4* __restrict__ csr) {
    int e = blockIdx.x * 256 + threadIdx.x;
    if (e >= NE) return;
    int dst = ei[NE + e];
    int src = ei[e];
    int p = atomicAdd(&cur[dst], 1);
    float2 eav = ((const float2*)ea)[e];
    int4 m;
    m.x = src;
    m.y = __float_as_int(eav.x);
    m.z = __float_as_int(eav.y);
    m.w = 0;
    csr[p] = m;
}

// ---------------- input projection ----------------
__global__ void k_input_proj(const float* __restrict__ x, const float* __restrict__ Wi,
                             const float* __restrict__ bi, float* __restrict__ h) {
    __shared__ float sW[IN_DIM * DD];
    __shared__ float sb[DD];
    int t = threadIdx.x;
    if (t < IN_DIM * DD) sW[t] = Wi[t];
    if (t < DD) sb[t] = bi[t];
    __syncthreads();
    int tid = blockIdx.x * blockDim.x + t;
    int n = tid / DD, d = tid - n * DD;
    if (n >= NN) return;
    float acc = sb[d];
    const float* xr = x + n * IN_DIM;
#pragma unroll
    for (int i = 0; i < IN_DIM; i++) acc += xr[i] * sW[i * DD + d];
    h[n * DS + d] = acc;
}

// ---------------- per-layer node pass: q,k,v,skip ----------------
__global__ void k_qkv_skip(const float* __restrict__ h,
                           const float* __restrict__ Wq, const float* __restrict__ bq,
                           const float* __restrict__ Wk, const float* __restrict__ bk,
                           const float* __restrict__ Wv, const float* __restrict__ bv,
                           const float* __restrict__ Ws, const float* __restrict__ bs,
                           float* __restrict__ q, float* __restrict__ k, float* __restrict__ v,
                           float* __restrict__ hout) {
    __shared__ float sWq[DD * DD], sWk[DD * DD], sWv[DD * DD], sWs[DD * DD];
    __shared__ float sb[4 * DD];
    for (int i = threadIdx.x; i < DD * DD; i += blockDim.x) {
        sWq[i] = Wq[i]; sWk[i] = Wk[i]; sWv[i] = Wv[i]; sWs[i] = Ws[i];
    }
    if (threadIdx.x < DD) {
        sb[threadIdx.x]          = bq[threadIdx.x];
        sb[DD + threadIdx.x]     = bk[threadIdx.x];
        sb[2 * DD + threadIdx.x] = bv[threadIdx.x];
        sb[3 * DD + threadIdx.x] = bs[threadIdx.x];
    }
    __syncthreads();
    int tid = blockIdx.x * blockDim.x + threadIdx.x;
    int n = tid / DD, d = tid - n * DD;
    if (n >= NN) return;
    float aq = sb[d], ak = sb[DD + d], av = sb[2 * DD + d], asv = sb[3 * DD + d];
    const float* hr = h + (size_t)n * DS;
#pragma unroll
    for (int i = 0; i < DD; i++) {
        float hv = hr[i];
        aq  += hv * sWq[i * DD + d];
        ak  += hv * sWk[i * DD + d];
        av  += hv * sWv[i * DD + d];
        asv += hv * sWs[i * DD + d];
    }
    q[n * DS + d] = aq;
    k[n * DS + d] = ak;
    v[n * DS + d] = av;
    hout[n * DS + d] = asv;
}

// ---------------- fused edge pass: online softmax + aggregate, no atomics ----------------
// 8 lanes per destination node; 32 nodes per 256-thread block. NN = 3125*32 exactly.
__global__ __launch_bounds__(256) void k_edge_fused(
    const int* __restrict__ rowptr, const int4* __restrict__ csr,
    const float* __restrict__ We, const float* __restrict__ q,
    const float* __restrict__ k, const float* __restrict__ v,
    float* __restrict__ hout) {
    __shared__ float sWe[EDGE_DIM * DD];
    if (threadIdx.x < EDGE_DIM * DD) sWe[threadIdx.x] = We[threadIdx.x];
    __syncthreads();
    int n = blockIdx.x * 32 + (threadIdx.x >> 3);
    int g = threadIdx.x & 7;
    if (n >= NN) return;
    int beg = rowptr[n], end = rowptr[n + 1];

    float qa[28];
    {
        const float4* qr = (const float4*)(q + (size_t)n * DS);
#pragma unroll
        for (int i = 0; i < 7; i++) {
            float4 t = qr[i];
            qa[4 * i] = t.x; qa[4 * i + 1] = t.y; qa[4 * i + 2] = t.z; qa[4 * i + 3] = t.w;
        }
    }

    float m[HH], l[HH], acc[DD];
#pragma unroll
    for (int hd = 0; hd < HH; hd++) { m[hd] = -INFINITY; l[hd] = 0.0f; }
#pragma unroll
    for (int j = 0; j < DD; j++) acc[j] = 0.0f;

    for (int p = beg + g; p < end; p += 8) {
        int4 meta = csr[p];
        int src = meta.x;
        float eax = __int_as_float(meta.y), eay = __int_as_float(meta.z);

        float kb[28];
        const float4* kr = (const float4*)(k + (size_t)src * DS);
#pragma unroll
        for (int i = 0; i < 7; i++) {
            float4 t = kr[i];
            kb[4 * i] = t.x; kb[4 * i + 1] = t.y; kb[4 * i + 2] = t.z; kb[4 * i + 3] = t.w;
        }
        float a[HH];
#pragma unroll
        for (int hd = 0; hd < HH; hd++) {
            float s = 0.0f;
#pragma unroll
            for (int c = 0; c < CC; c++) {
                int j = hd * CC + c;
                float ev = eax * sWe[j] + eay * sWe[DD + j];
                s += qa[j] * (kb[j] + ev);
            }
            a[hd] = s * INV_SQRT_C;
        }

        float vb[28];
        const float4* vr = (const float4*)(v + (size_t)src * DS);
#pragma unroll
        for (int i = 0; i < 7; i++) {
            float4 t = vr[i];
            vb[4 * i] = t.x; vb[4 * i + 1] = t.y; vb[4 * i + 2] = t.z; vb[4 * i + 3] = t.w;
        }
#pragma unroll
        for (int hd = 0; hd < HH; hd++) {
            float mn = fmaxf(m[hd], a[hd]);
            float sc = __expf(m[hd] - mn);   // -inf - finite -> exp(-inf)=0, no NaN
            float cf = __expf(a[hd] - mn);
            m[hd] = mn;
            l[hd] = l[hd] * sc + cf;
#pragma unroll
            for (int c = 0; c < CC; c++) {
                int j = hd * CC + c;
                float ev = eax * sWe[j] + eay * sWe[DD + j];
                acc[j] = acc[j] * sc + cf * (vb[j] + ev);
            }
        }
    }

    // merge the 8 lanes of this node (contiguous, 8-aligned -> xor masks 1,2,4 stay in-group)
#pragma unroll
    for (int off = 1; off < 8; off <<= 1) {
#pragma unroll
        for (int hd = 0; hd < HH; hd++) {
            float m2 = __shfl_xor(m[hd], off, 64);
            float l2 = __shfl_xor(l[hd], off, 64);
            float mn = fmaxf(m[hd], m2);
            float s1 = (m[hd] > -INFINITY) ? __expf(m[hd] - mn) : 0.0f;
            float s2 = (m2 > -INFINITY) ? __expf(m2 - mn) : 0.0f;
            l[hd] = l[hd] * s1 + l2 * s2;
#pragma unroll
            for (int c = 0; c < CC; c++) {
                int j = hd * CC + c;
                float a2 = __shfl_xor(acc[j], off, 64);
                acc[j] = acc[j] * s1 + a2 * s2;
            }
            m[hd] = mn;
        }
    }

    if (g == 0) {
        float* ho = hout + (size_t)n * DS;
#pragma unroll
        for (int hd = 0; hd < HH; hd++) {
            float inv = 1.0f / (l[hd] + 1e-16f);
#pragma unroll
            for (int c = 0; c < CC; c++) {
                int j = hd * CC + c;
                ho[j] += acc[j] * inv;
            }
        }
    }
}

// ---------------- output head ----------------
__global__ void k_head(const float* __restrict__ h, const float* __restrict__ Wo,
                       const float* __restrict__ bo, float* __restrict__ out) {
    __shared__ float sW[DD];
    __shared__ float sb0;
    if (threadIdx.x < DD) sW[threadIdx.x] = Wo[threadIdx.x];
    if (threadIdx.x == 0) sb0 = bo[0];
    __syncthreads();
    int n = blockIdx.x * blockDim.x + threadIdx.x;
    if (n >= NN) return;
    float acc = sb0;
    const float* hr = h + (size_t)n * DS;
#pragma unroll
    for (int i = 0; i < DD; i++) acc += hr[i] * sW[i];
    out[n] = 1.0f / (1.0f + __expf(-acc));
}

extern "C" void kernel_launch(void* const* d_in, const int* in_sizes, int n_in,
                              void* d_out, int out_size, void* d_ws, size_t ws_size,
                              hipStream_t stream) {
    const float* x     = (const float*)d_in[0];
    const int*   ei    = (const int*)d_in[1];     // [2,E]: src=[0..E), dst=[E..2E)
    const float* ea    = (const float*)d_in[2];   // [E,2]
    const float* Wi    = (const float*)d_in[3];
    const float* bi    = (const float*)d_in[4];
    const float* Wq    = (const float*)d_in[5];
    const float* bq    = (const float*)d_in[6];
    const float* Wk    = (const float*)d_in[7];
    const float* bk    = (const float*)d_in[8];
    const float* Wv    = (const float*)d_in[9];
    const float* bv    = (const float*)d_in[10];
    const float* We    = (const float*)d_in[11];
    const float* Wskip = (const float*)d_in[12];
    const float* bskip = (const float*)d_in[13];
    const float* Wo    = (const float*)d_in[14];
    const float* bo    = (const float*)d_in[15];
    float* out = (float*)d_out;
    (void)in_sizes; (void)n_in; (void)out_size; (void)ws_size;

    char* wsb = (char*)d_ws;
    size_t off = 0;
    auto alloc = [&](size_t bytes) {
        void* p = wsb + off;
        off += (bytes + 15) & ~(size_t)15;
        return p;
    };
    int4*  csr    = (int4*)alloc((size_t)NE * sizeof(int4));      // 25.6 MB
    float* hA     = (float*)alloc((size_t)NN * DS * sizeof(float));
    float* hB     = (float*)alloc((size_t)NN * DS * sizeof(float));
    float* q      = (float*)alloc((size_t)NN * DS * sizeof(float));
    float* k      = (float*)alloc((size_t)NN * DS * sizeof(float));
    float* v      = (float*)alloc((size_t)NN * DS * sizeof(float));
    int*   deg    = (int*)alloc((size_t)NN * sizeof(int));
    int*   excl   = (int*)alloc((size_t)NN * sizeof(int));
    int*   bsum   = (int*)alloc((size_t)NB1 * sizeof(int));
    int*   rowptr = (int*)alloc((size_t)(NN + 1) * sizeof(int));
    int*   cur    = (int*)alloc((size_t)NN * sizeof(int));

    dim3 blk(256);
    int gN  = (NN + 255) / 256;         // 391
    int gE  = (NE + 255) / 256;         // 6250
    int gND = (NN * DD + 255) / 256;    // 9766
    int gF  = NN / 32;                  // 3125 (exact)

    // CSR build (every call — ws is re-poisoned)
    k_zero_deg<<<gN, blk, 0, stream>>>(deg);
    k_hist<<<gE, blk, 0, stream>>>(ei, deg);
    k_scan1<<<gN, blk, 0, stream>>>(deg, excl, bsum);
    k_scan2<<<1, dim3(512), 0, stream>>>(bsum);
    k_scan3<<<gN, blk, 0, stream>>>(excl, bsum, rowptr, cur);
    k_scatter<<<gE, blk, 0, stream>>>(ei, ea, cur, csr);

    k_input_proj<<<gND, blk, 0, stream>>>(x, Wi, bi, hA);

    float* hc = hA;
    float* hn = hB;
    for (int l = 0; l < 3; l++) {
        k_qkv_skip<<<gND, blk, 0, stream>>>(hc,
                                            Wq + (size_t)l * DD * DD, bq + (size_t)l * DD,
                                            Wk + (size_t)l * DD * DD, bk + (size_t)l * DD,
                                            Wv + (size_t)l * DD * DD, bv + (size_t)l * DD,
                                            Wskip + (size_t)l * DD * DD, bskip + (size_t)l * DD,
                                            q, k, v, hn);
        k_edge_fused<<<gF, blk, 0, stream>>>(rowptr, csr,
                                             We + (size_t)l * EDGE_DIM * DD,
                                             q, k, v, hn);
        float* t = hc; hc = hn; hn = t;
    }
    k_head<<<gN, blk, 0, stream>>>(hc, Wo, bo, out);
}

// Round 3
// 522.350 us; speedup vs baseline: 16.2506x; 1.3779x over previous
//
#include <hip/hip_runtime.h>
#include <hip/hip_bf16.h>
#include <math.h>

#define NN 100000      // nodes
#define NE 1600000     // edges
#define IN_DIM 6
#define EDGE_DIM 2
#define HH 5           // heads
#define CC 5           // channels/head
#define DD 25          // hidden = HH*CC
#define DS 32          // padded fp32 row stride (128B rows)
#define KVS 64         // bf16 kv record stride in shorts: k[0..24] @0, v[0..24] @32 -> 128 B
#define INV_SQRT_C 0.4472135954999579f
#define SCAN_B 256
#define NB1 ((NN + SCAN_B - 1) / SCAN_B)   // 391

// ---------------- CSR build ----------------
__global__ void k_zero_deg(int* __restrict__ deg) {
    int i = blockIdx.x * 256 + threadIdx.x;
    if (i < NN) deg[i] = 0;
}

__global__ void k_hist(const int* __restrict__ ei, int* __restrict__ deg) {
    int e = blockIdx.x * 256 + threadIdx.x;
    if (e < NE) atomicAdd(&deg[ei[NE + e]], 1);
}

__global__ void k_scan1(const int* __restrict__ deg, int* __restrict__ excl,
                        int* __restrict__ bsum) {
    __shared__ int s[SCAN_B];
    int i = blockIdx.x * SCAN_B + threadIdx.x;
    int v = (i < NN) ? deg[i] : 0;
    s[threadIdx.x] = v;
    __syncthreads();
    for (int off = 1; off < SCAN_B; off <<= 1) {
        int t = (threadIdx.x >= off) ? s[threadIdx.x - off] : 0;
        __syncthreads();
        s[threadIdx.x] += t;
        __syncthreads();
    }
    if (i < NN) excl[i] = s[threadIdx.x] - v;
    if (threadIdx.x == SCAN_B - 1) bsum[blockIdx.x] = s[SCAN_B - 1];
}

__global__ void k_scan2(int* __restrict__ bsum) {   // single block of 512
    __shared__ int s[512];
    int t = threadIdx.x;
    int v = (t < NB1) ? bsum[t] : 0;
    s[t] = v;
    __syncthreads();
    for (int off = 1; off < 512; off <<= 1) {
        int u = (t >= off) ? s[t - off] : 0;
        __syncthreads();
        s[t] += u;
        __syncthreads();
    }
    if (t < NB1) bsum[t] = s[t] - v;   // exclusive block offsets
}

__global__ void k_scan3(const int* __restrict__ excl, const int* __restrict__ bsum,
                        int* __restrict__ rowptr, int* __restrict__ cur) {
    int i = blockIdx.x * 256 + threadIdx.x;
    if (i < NN) {
        int r = excl[i] + bsum[i / SCAN_B];
        rowptr[i] = r;
        cur[i] = r;
    }
    if (i == 0) rowptr[NN] = NE;
}

__global__ void k_scatter(const int* __restrict__ ei, const float* __restrict__ ea,
                          int* __restrict__ cur, int4* __restrict__ csr) {
    int e = blockIdx.x * 256 + threadIdx.x;
    if (e >= NE) return;
    int dst = ei[NE + e];
    int src = ei[e];
    int p = atomicAdd(&cur[dst], 1);
    float2 eav = ((const float2*)ea)[e];
    int4 m;
    m.x = src;
    m.y = __float_as_int(eav.x);
    m.z = __float_as_int(eav.y);
    m.w = 0;
    csr[p] = m;
}

// ---------------- input projection ----------------
__global__ void k_input_proj(const float* __restrict__ x, const float* __restrict__ Wi,
                             const float* __restrict__ bi, float* __restrict__ h) {
    __shared__ float sW[IN_DIM * DD];
    __shared__ float sb[DD];
    int t = threadIdx.x;
    if (t < IN_DIM * DD) sW[t] = Wi[t];
    if (t < DD) sb[t] = bi[t];
    __syncthreads();
    int tid = blockIdx.x * blockDim.x + t;
    int n = tid / DD, d = tid - n * DD;
    if (n >= NN) return;
    float acc = sb[d];
    const float* xr = x + n * IN_DIM;
#pragma unroll
    for (int i = 0; i < IN_DIM; i++) acc += xr[i] * sW[i * DD + d];
    h[n * DS + d] = acc;
}

// ------- per-layer node pass: q (pre-scaled fp32), kv (packed bf16), skip -------
__global__ void k_qkv_skip(const float* __restrict__ h,
                           const float* __restrict__ Wq, const float* __restrict__ bq,
                           const float* __restrict__ Wk, const float* __restrict__ bk,
                           const float* __restrict__ Wv, const float* __restrict__ bv,
                           const float* __restrict__ Ws, const float* __restrict__ bs,
                           float* __restrict__ q, __hip_bfloat16* __restrict__ kv,
                           float* __restrict__ hout) {
    __shared__ float sWq[DD * DD], sWk[DD * DD], sWv[DD * DD], sWs[DD * DD];
    __shared__ float sb[4 * DD];
    for (int i = threadIdx.x; i < DD * DD; i += blockDim.x) {
        sWq[i] = Wq[i]; sWk[i] = Wk[i]; sWv[i] = Wv[i]; sWs[i] = Ws[i];
    }
    if (threadIdx.x < DD) {
        sb[threadIdx.x]          = bq[threadIdx.x];
        sb[DD + threadIdx.x]     = bk[threadIdx.x];
        sb[2 * DD + threadIdx.x] = bv[threadIdx.x];
        sb[3 * DD + threadIdx.x] = bs[threadIdx.x];
    }
    __syncthreads();
    int tid = blockIdx.x * blockDim.x + threadIdx.x;
    int n = tid / DD, d = tid - n * DD;
    if (n >= NN) return;
    float aq = sb[d], ak = sb[DD + d], av = sb[2 * DD + d], asv = sb[3 * DD + d];
    const float* hr = h + (size_t)n * DS;
#pragma unroll
    for (int i = 0; i < DD; i++) {
        float hv = hr[i];
        aq  += hv * sWq[i * DD + d];
        ak  += hv * sWk[i * DD + d];
        av  += hv * sWv[i * DD + d];
        asv += hv * sWs[i * DD + d];
    }
    q[(size_t)n * DS + d] = aq * INV_SQRT_C;       // fold 1/sqrt(C) into q
    kv[(size_t)n * KVS + d]      = __float2bfloat16(ak);
    kv[(size_t)n * KVS + 32 + d] = __float2bfloat16(av);
    hout[(size_t)n * DS + d] = asv;
}

// bf16 pair expansion: u32 holding two bf16 -> two fp32 (exact, bit placement)
__device__ __forceinline__ float bflo(unsigned int u) { return __uint_as_float(u << 16); }
__device__ __forceinline__ float bfhi(unsigned int u) { return __uint_as_float(u & 0xffff0000u); }

// ---------------- fused edge pass: plain-exp softmax + aggregate, no atomics ----------------
// 8 lanes per destination node; 32 nodes per 256-thread block. NN = 3125*32 exactly.
__global__ __launch_bounds__(256) void k_edge_fused(
    const int* __restrict__ rowptr, const int4* __restrict__ csr,
    const float* __restrict__ We, const float* __restrict__ q,
    const __hip_bfloat16* __restrict__ kv, float* __restrict__ hout) {
    __shared__ float sWe[EDGE_DIM * DD];
    if (threadIdx.x < EDGE_DIM * DD) sWe[threadIdx.x] = We[threadIdx.x];
    __syncthreads();
    int n = blockIdx.x * 32 + (threadIdx.x >> 3);
    int g = threadIdx.x & 7;
    if (n >= NN) return;
    int beg = rowptr[n], end = rowptr[n + 1];

    float qa[28];
    {
        const float4* qr = (const float4*)(q + (size_t)n * DS);
#pragma unroll
        for (int i = 0; i < 7; i++) {
            float4 t = qr[i];
            qa[4 * i] = t.x; qa[4 * i + 1] = t.y; qa[4 * i + 2] = t.z; qa[4 * i + 3] = t.w;
        }
    }
    // per-node q . We (already carries 1/sqrt(C) via q pre-scale)
    float qwx[HH], qwy[HH];
#pragma unroll
    for (int hd = 0; hd < HH; hd++) {
        float sx = 0.0f, sy = 0.0f;
#pragma unroll
        for (int c = 0; c < CC; c++) {
            int j = hd * CC + c;
            sx += qa[j] * sWe[j];
            sy += qa[j] * sWe[DD + j];
        }
        qwx[hd] = sx; qwy[hd] = sy;
    }

    float l[HH], Sx[HH], Sy[HH], accv[DD];
#pragma unroll
    for (int hd = 0; hd < HH; hd++) { l[hd] = 0.0f; Sx[hd] = 0.0f; Sy[hd] = 0.0f; }
#pragma unroll
    for (int j = 0; j < DD; j++) accv[j] = 0.0f;

    for (int p = beg + g; p < end; p += 8) {
        int4 meta = csr[p];
        int src = meta.x;
        float eax = __int_as_float(meta.y), eay = __int_as_float(meta.z);

        // one 128-B line: k bf16[25] @ shorts 0..24, v bf16[25] @ shorts 32..56
        const uint4* kr = (const uint4*)(kv + (size_t)src * KVS);
        uint4 r0 = kr[0], r1 = kr[1], r2 = kr[2], r3 = kr[3];   // k
        uint4 r4 = kr[4], r5 = kr[5], r6 = kr[6], r7 = kr[7];   // v

        float kb[26];
        kb[0]=bflo(r0.x); kb[1]=bfhi(r0.x); kb[2]=bflo(r0.y); kb[3]=bfhi(r0.y);
        kb[4]=bflo(r0.z); kb[5]=bfhi(r0.z); kb[6]=bflo(r0.w); kb[7]=bfhi(r0.w);
        kb[8]=bflo(r1.x); kb[9]=bfhi(r1.x); kb[10]=bflo(r1.y); kb[11]=bfhi(r1.y);
        kb[12]=bflo(r1.z); kb[13]=bfhi(r1.z); kb[14]=bflo(r1.w); kb[15]=bfhi(r1.w);
        kb[16]=bflo(r2.x); kb[17]=bfhi(r2.x); kb[18]=bflo(r2.y); kb[19]=bfhi(r2.y);
        kb[20]=bflo(r2.z); kb[21]=bfhi(r2.z); kb[22]=bflo(r2.w); kb[23]=bfhi(r2.w);
        kb[24]=bflo(r3.x);

        float al[HH];
#pragma unroll
        for (int hd = 0; hd < HH; hd++) {
            float s = eax * qwx[hd] + eay * qwy[hd];
#pragma unroll
            for (int c = 0; c < CC; c++) {
                int j = hd * CC + c;
                s += qa[j] * kb[j];
            }
            al[hd] = __expf(s);
        }

        float vb[26];
        vb[0]=bflo(r4.x); vb[1]=bfhi(r4.x); vb[2]=bflo(r4.y); vb[3]=bfhi(r4.y);
        vb[4]=bflo(r4.z); vb[5]=bfhi(r4.z); vb[6]=bflo(r4.w); vb[7]=bfhi(r4.w);
        vb[8]=bflo(r5.x); vb[9]=bfhi(r5.x); vb[10]=bflo(r5.y); vb[11]=bfhi(r5.y);
        vb[12]=bflo(r5.z); vb[13]=bfhi(r5.z); vb[14]=bflo(r5.w); vb[15]=bfhi(r5.w);
        vb[16]=bflo(r6.x); vb[17]=bfhi(r6.x); vb[18]=bflo(r6.y); vb[19]=bfhi(r6.y);
        vb[20]=bflo(r6.z); vb[21]=bfhi(r6.z); vb[22]=bflo(r6.w); vb[23]=bfhi(r6.w);
        vb[24]=bflo(r7.x);

#pragma unroll
        for (int hd = 0; hd < HH; hd++) {
            float cf = al[hd];
            l[hd]  += cf;
            Sx[hd] += cf * eax;
            Sy[hd] += cf * eay;
#pragma unroll
            for (int c = 0; c < CC; c++) {
                int j = hd * CC + c;
                accv[j] += cf * vb[j];
            }
        }
    }

    // merge 8 lanes per node (pure sums)
#pragma unroll
    for (int off = 1; off < 8; off <<= 1) {
#pragma unroll
        for (int hd = 0; hd < HH; hd++) {
            l[hd]  += __shfl_xor(l[hd], off, 64);
            Sx[hd] += __shfl_xor(Sx[hd], off, 64);
            Sy[hd] += __shfl_xor(Sy[hd], off, 64);
        }
#pragma unroll
        for (int j = 0; j < DD; j++) accv[j] += __shfl_xor(accv[j], off, 64);
    }

    if (g == 0) {
        float* ho = hout + (size_t)n * DS;
#pragma unroll
        for (int hd = 0; hd < HH; hd++) {
            float inv = 1.0f / (l[hd] + 1e-16f);
#pragma unroll
            for (int c = 0; c < CC; c++) {
                int j = hd * CC + c;
                ho[j] += (accv[j] + Sx[hd] * sWe[j] + Sy[hd] * sWe[DD + j]) * inv;
            }
        }
    }
}

// ---------------- output head ----------------
__global__ void k_head(const float* __restrict__ h, const float* __restrict__ Wo,
                       const float* __restrict__ bo, float* __restrict__ out) {
    __shared__ float sW[DD];
    __shared__ float sb0;
    if (threadIdx.x < DD) sW[threadIdx.x] = Wo[threadIdx.x];
    if (threadIdx.x == 0) sb0 = bo[0];
    __syncthreads();
    int n = blockIdx.x * blockDim.x + threadIdx.x;
    if (n >= NN) return;
    float acc = sb0;
    const float* hr = h + (size_t)n * DS;
#pragma unroll
    for (int i = 0; i < DD; i++) acc += hr[i] * sW[i];
    out[n] = 1.0f / (1.0f + __expf(-acc));
}

extern "C" void kernel_launch(void* const* d_in, const int* in_sizes, int n_in,
                              void* d_out, int out_size, void* d_ws, size_t ws_size,
                              hipStream_t stream) {
    const float* x     = (const float*)d_in[0];
    const int*   ei    = (const int*)d_in[1];     // [2,E]: src=[0..E), dst=[E..2E)
    const float* ea    = (const float*)d_in[2];   // [E,2]
    const float* Wi    = (const float*)d_in[3];
    const float* bi    = (const float*)d_in[4];
    const float* Wq    = (const float*)d_in[5];
    const float* bq    = (const float*)d_in[6];
    const float* Wk    = (const float*)d_in[7];
    const float* bk    = (const float*)d_in[8];
    const float* Wv    = (const float*)d_in[9];
    const float* bv    = (const float*)d_in[10];
    const float* We    = (const float*)d_in[11];
    const float* Wskip = (const float*)d_in[12];
    const float* bskip = (const float*)d_in[13];
    const float* Wo    = (const float*)d_in[14];
    const float* bo    = (const float*)d_in[15];
    float* out = (float*)d_out;
    (void)in_sizes; (void)n_in; (void)out_size; (void)ws_size;

    char* wsb = (char*)d_ws;
    size_t off = 0;
    auto alloc = [&](size_t bytes) {
        void* p = wsb + off;
        off += (bytes + 127) & ~(size_t)127;
        return p;
    };
    int4*  csr    = (int4*)alloc((size_t)NE * sizeof(int4));                 // 25.6 MB
    __hip_bfloat16* kvrec = (__hip_bfloat16*)alloc((size_t)NN * KVS * 2);    // 12.8 MB
    float* hA     = (float*)alloc((size_t)NN * DS * sizeof(float));
    float* hB     = (float*)alloc((size_t)NN * DS * sizeof(float));
    float* q      = (float*)alloc((size_t)NN * DS * sizeof(float));
    int*   deg    = (int*)alloc((size_t)NN * sizeof(int));
    int*   excl   = (int*)alloc((size_t)NN * sizeof(int));
    int*   bsum   = (int*)alloc((size_t)NB1 * sizeof(int));
    int*   rowptr = (int*)alloc((size_t)(NN + 1) * sizeof(int));
    int*   cur    = (int*)alloc((size_t)NN * sizeof(int));

    dim3 blk(256);
    int gN  = (NN + 255) / 256;         // 391
    int gE  = (NE + 255) / 256;         // 6250
    int gND = (NN * DD + 255) / 256;    // 9766
    int gF  = NN / 32;                  // 3125 (exact)

    // CSR build (every call — ws is re-poisoned)
    k_zero_deg<<<gN, blk, 0, stream>>>(deg);
    k_hist<<<gE, blk, 0, stream>>>(ei, deg);
    k_scan1<<<gN, blk, 0, stream>>>(deg, excl, bsum);
    k_scan2<<<1, dim3(512), 0, stream>>>(bsum);
    k_scan3<<<gN, blk, 0, stream>>>(excl, bsum, rowptr, cur);
    k_scatter<<<gE, blk, 0, stream>>>(ei, ea, cur, csr);

    k_input_proj<<<gND, blk, 0, stream>>>(x, Wi, bi, hA);

    float* hc = hA;
    float* hn = hB;
    for (int l = 0; l < 3; l++) {
        k_qkv_skip<<<gND, blk, 0, stream>>>(hc,
                                            Wq + (size_t)l * DD * DD, bq + (size_t)l * DD,
                                            Wk + (size_t)l * DD * DD, bk + (size_t)l * DD,
                                            Wv + (size_t)l * DD * DD, bv + (size_t)l * DD,
                                            Wskip + (size_t)l * DD * DD, bskip + (size_t)l * DD,
                                            q, kvrec, hn);
        k_edge_fused<<<gF, blk, 0, stream>>>(rowptr, csr,
                                             We + (size_t)l * EDGE_DIM * DD,
                                             q, kvrec, hn);
        float* t = hc; hc = hn; hn = t;
    }
    k_head<<<gN, blk, 0, stream>>>(hc, Wo, bo, out);
}

// Round 4
// 474.356 us; speedup vs baseline: 17.8948x; 1.1012x over previous
//
#include <hip/hip_runtime.h>
#include <hip/hip_bf16.h>
#include <math.h>

#define NN 100000      // nodes
#define NE 1600000     // edges
#define IN_DIM 6
#define EDGE_DIM 2
#define HH 5           // heads
#define CC 5           // channels/head
#define DD 25          // hidden = HH*CC
#define DS 32          // padded fp32 row stride (128B rows)
#define KVS 64         // bf16 kv record stride in shorts: k[0..24] @0, v[0..24] @32 -> 128 B
#define INV_SQRT_C 0.4472135954999579f
#define SCAN_B 256
#define NB1 ((NN + SCAN_B - 1) / SCAN_B)   // 391
#define NBUCK 8
#define BUCK_W 12500   // nodes per bucket
#define NCH 800        // scatter chunks
#define CHE (NE / NCH) // 2000 edges per chunk

__device__ __forceinline__ unsigned int f2bf(float f) {   // fp32 -> bf16 bits (RNE)
    unsigned int u = __float_as_uint(f);
    return (u + 0x7fffu + ((u >> 16) & 1u)) >> 16;
}
__device__ __forceinline__ float bflo(unsigned int u) { return __uint_as_float(u << 16); }
__device__ __forceinline__ float bfhi(unsigned int u) { return __uint_as_float(u & 0xffff0000u); }

// ---------------- CSR build ----------------
__global__ void k_zero_deg(int* __restrict__ deg) {
    int i = blockIdx.x * 256 + threadIdx.x;
    if (i < NN) deg[i] = 0;
}

__global__ void k_hist(const int* __restrict__ ei, int* __restrict__ deg) {
    int e = (blockIdx.x * 256 + threadIdx.x) * 4;
    if (e + 3 < NE) {
        int4 d = *(const int4*)(ei + NE + e);
        atomicAdd(&deg[d.x], 1);
        atomicAdd(&deg[d.y], 1);
        atomicAdd(&deg[d.z], 1);
        atomicAdd(&deg[d.w], 1);
    } else {
        for (int k = e; k < NE; k++) atomicAdd(&deg[ei[NE + k]], 1);
    }
}

__global__ void k_scan1(const int* __restrict__ deg, int* __restrict__ excl,
                        int* __restrict__ bsum) {
    __shared__ int s[SCAN_B];
    int i = blockIdx.x * SCAN_B + threadIdx.x;
    int v = (i < NN) ? deg[i] : 0;
    s[threadIdx.x] = v;
    __syncthreads();
    for (int off = 1; off < SCAN_B; off <<= 1) {
        int t = (threadIdx.x >= off) ? s[threadIdx.x - off] : 0;
        __syncthreads();
        s[threadIdx.x] += t;
        __syncthreads();
    }
    if (i < NN) excl[i] = s[threadIdx.x] - v;
    if (threadIdx.x == SCAN_B - 1) bsum[blockIdx.x] = s[SCAN_B - 1];
}

__global__ void k_scan2(int* __restrict__ bsum) {   // single block of 512
    __shared__ int s[512];
    int t = threadIdx.x;
    int v = (t < NB1) ? bsum[t] : 0;
    s[t] = v;
    __syncthreads();
    for (int off = 1; off < 512; off <<= 1) {
        int u = (t >= off) ? s[t - off] : 0;
        __syncthreads();
        s[t] += u;
        __syncthreads();
    }
    if (t < NB1) bsum[t] = s[t] - v;   // exclusive block offsets
}

__global__ void k_scan3(const int* __restrict__ excl, const int* __restrict__ bsum,
                        int* __restrict__ rowptr, int* __restrict__ cur) {
    int i = blockIdx.x * 256 + threadIdx.x;
    if (i < NN) {
        int r = excl[i] + bsum[i / SCAN_B];
        rowptr[i] = r;
        cur[i] = r;
    }
    if (i == 0) rowptr[NN] = NE;
}

// bucketed scatter: block handles bucket (blockIdx&7) of chunk (blockIdx>>3).
// If blockIdx%8 tracks XCD, each CSR bucket region is written by one XCD only.
__global__ __launch_bounds__(256) void k_scatter(
    const int* __restrict__ ei, const float* __restrict__ ea,
    int* __restrict__ cur, uint2* __restrict__ csr) {
    int bucket = blockIdx.x & (NBUCK - 1);
    int base = (blockIdx.x >> 3) * CHE;
    for (int i = threadIdx.x; i < CHE; i += 256) {
        int e = base + i;
        int dst = ei[NE + e];
        if ((unsigned)dst / BUCK_W == (unsigned)bucket) {
            int src = ei[e];
            float2 eav = ((const float2*)ea)[e];
            int p = atomicAdd(&cur[dst], 1);
            uint2 rec;
            rec.x = (unsigned)src;
            rec.y = f2bf(eav.x) | (f2bf(eav.y) << 16);
            csr[p] = rec;
        }
    }
}

// ---------------- input projection ----------------
__global__ void k_input_proj(const float* __restrict__ x, const float* __restrict__ Wi,
                             const float* __restrict__ bi, float* __restrict__ h) {
    __shared__ float sW[IN_DIM * DD];
    __shared__ float sb[DD];
    int t = threadIdx.x;
    if (t < IN_DIM * DD) sW[t] = Wi[t];
    if (t < DD) sb[t] = bi[t];
    __syncthreads();
    int tid = blockIdx.x * blockDim.x + t;
    int n = tid / DD, d = tid - n * DD;
    if (n >= NN) return;
    float acc = sb[d];
    const float* xr = x + n * IN_DIM;
#pragma unroll
    for (int i = 0; i < IN_DIM; i++) acc += xr[i] * sW[i * DD + d];
    h[n * DS + d] = acc;
}

// ------- per-layer node pass: q (pre-scaled fp32), kv (packed bf16), skip -------
__global__ void k_qkv_skip(const float* __restrict__ h,
                           const float* __restrict__ Wq, const float* __restrict__ bq,
                           const float* __restrict__ Wk, const float* __restrict__ bk,
                           const float* __restrict__ Wv, const float* __restrict__ bv,
                           const float* __restrict__ Ws, const float* __restrict__ bs,
                           float* __restrict__ q, __hip_bfloat16* __restrict__ kv,
                           float* __restrict__ hout) {
    __shared__ float sWq[DD * DD], sWk[DD * DD], sWv[DD * DD], sWs[DD * DD];
    __shared__ float sb[4 * DD];
    for (int i = threadIdx.x; i < DD * DD; i += blockDim.x) {
        sWq[i] = Wq[i]; sWk[i] = Wk[i]; sWv[i] = Wv[i]; sWs[i] = Ws[i];
    }
    if (threadIdx.x < DD) {
        sb[threadIdx.x]          = bq[threadIdx.x];
        sb[DD + threadIdx.x]     = bk[threadIdx.x];
        sb[2 * DD + threadIdx.x] = bv[threadIdx.x];
        sb[3 * DD + threadIdx.x] = bs[threadIdx.x];
    }
    __syncthreads();
    int tid = blockIdx.x * blockDim.x + threadIdx.x;
    int n = tid / DD, d = tid - n * DD;
    if (n >= NN) return;
    float aq = sb[d], ak = sb[DD + d], av = sb[2 * DD + d], asv = sb[3 * DD + d];
    const float* hr = h + (size_t)n * DS;
#pragma unroll
    for (int i = 0; i < DD; i++) {
        float hv = hr[i];
        aq  += hv * sWq[i * DD + d];
        ak  += hv * sWk[i * DD + d];
        av  += hv * sWv[i * DD + d];
        asv += hv * sWs[i * DD + d];
    }
    q[(size_t)n * DS + d] = aq * INV_SQRT_C;       // fold 1/sqrt(C) into q
    kv[(size_t)n * KVS + d]      = __float2bfloat16(ak);
    kv[(size_t)n * KVS + 32 + d] = __float2bfloat16(av);
    hout[(size_t)n * DS + d] = asv;
}

// ---------------- fused edge pass: plain-exp softmax + aggregate, no atomics ----------------
// 8 lanes per destination node; 32 nodes per 256-thread block. NN = 3125*32 exactly.
__global__ __launch_bounds__(256) void k_edge_fused(
    const int* __restrict__ rowptr, const uint2* __restrict__ csr,
    const float* __restrict__ We, const float* __restrict__ q,
    const __hip_bfloat16* __restrict__ kv, float* __restrict__ hout) {
    __shared__ float sWe[EDGE_DIM * DD];
    if (threadIdx.x < EDGE_DIM * DD) sWe[threadIdx.x] = We[threadIdx.x];
    __syncthreads();
    int n = blockIdx.x * 32 + (threadIdx.x >> 3);
    int g = threadIdx.x & 7;
    if (n >= NN) return;
    int beg = rowptr[n], end = rowptr[n + 1];

    float qa[28];
    {
        const float4* qr = (const float4*)(q + (size_t)n * DS);
#pragma unroll
        for (int i = 0; i < 7; i++) {
            float4 t = qr[i];
            qa[4 * i] = t.x; qa[4 * i + 1] = t.y; qa[4 * i + 2] = t.z; qa[4 * i + 3] = t.w;
        }
    }
    // per-node q . We (already carries 1/sqrt(C) via q pre-scale)
    float qwx[HH], qwy[HH];
#pragma unroll
    for (int hd = 0; hd < HH; hd++) {
        float sx = 0.0f, sy = 0.0f;
#pragma unroll
        for (int c = 0; c < CC; c++) {
            int j = hd * CC + c;
            sx += qa[j] * sWe[j];
            sy += qa[j] * sWe[DD + j];
        }
        qwx[hd] = sx; qwy[hd] = sy;
    }

    float l[HH], Sx[HH], Sy[HH], accv[DD];
#pragma unroll
    for (int hd = 0; hd < HH; hd++) { l[hd] = 0.0f; Sx[hd] = 0.0f; Sy[hd] = 0.0f; }
#pragma unroll
    for (int j = 0; j < DD; j++) accv[j] = 0.0f;

    for (int p = beg + g; p < end; p += 8) {
        uint2 rec = csr[p];
        int src = (int)rec.x;
        float eax = bflo(rec.y), eay = bfhi(rec.y);

        // one 128-B line: k bf16[25] @ shorts 0..24, v bf16[25] @ shorts 32..56
        const uint4* kr = (const uint4*)(kv + (size_t)src * KVS);
        uint4 r0 = kr[0], r1 = kr[1], r2 = kr[2], r3 = kr[3];   // k
        uint4 r4 = kr[4], r5 = kr[5], r6 = kr[6], r7 = kr[7];   // v

        float kb[26];
        kb[0]=bflo(r0.x); kb[1]=bfhi(r0.x); kb[2]=bflo(r0.y); kb[3]=bfhi(r0.y);
        kb[4]=bflo(r0.z); kb[5]=bfhi(r0.z); kb[6]=bflo(r0.w); kb[7]=bfhi(r0.w);
        kb[8]=bflo(r1.x); kb[9]=bfhi(r1.x); kb[10]=bflo(r1.y); kb[11]=bfhi(r1.y);
        kb[12]=bflo(r1.z); kb[13]=bfhi(r1.z); kb[14]=bflo(r1.w); kb[15]=bfhi(r1.w);
        kb[16]=bflo(r2.x); kb[17]=bfhi(r2.x); kb[18]=bflo(r2.y); kb[19]=bfhi(r2.y);
        kb[20]=bflo(r2.z); kb[21]=bfhi(r2.z); kb[22]=bflo(r2.w); kb[23]=bfhi(r2.w);
        kb[24]=bflo(r3.x);

        float al[HH];
#pragma unroll
        for (int hd = 0; hd < HH; hd++) {
            float s = eax * qwx[hd] + eay * qwy[hd];
#pragma unroll
            for (int c = 0; c < CC; c++) {
                int j = hd * CC + c;
                s += qa[j] * kb[j];
            }
            al[hd] = __expf(s);
        }

        float vb[26];
        vb[0]=bflo(r4.x); vb[1]=bfhi(r4.x); vb[2]=bflo(r4.y); vb[3]=bfhi(r4.y);
        vb[4]=bflo(r4.z); vb[5]=bfhi(r4.z); vb[6]=bflo(r4.w); vb[7]=bfhi(r4.w);
        vb[8]=bflo(r5.x); vb[9]=bfhi(r5.x); vb[10]=bflo(r5.y); vb[11]=bfhi(r5.y);
        vb[12]=bflo(r5.z); vb[13]=bfhi(r5.z); vb[14]=bflo(r5.w); vb[15]=bfhi(r5.w);
        vb[16]=bflo(r6.x); vb[17]=bfhi(r6.x); vb[18]=bflo(r6.y); vb[19]=bfhi(r6.y);
        vb[20]=bflo(r6.z); vb[21]=bfhi(r6.z); vb[22]=bflo(r6.w); vb[23]=bfhi(r6.w);
        vb[24]=bflo(r7.x);

#pragma unroll
        for (int hd = 0; hd < HH; hd++) {
            float cf = al[hd];
            l[hd]  += cf;
            Sx[hd] += cf * eax;
            Sy[hd] += cf * eay;
#pragma unroll
            for (int c = 0; c < CC; c++) {
                int j = hd * CC + c;
                accv[j] += cf * vb[j];
            }
        }
    }

    // merge 8 lanes per node (pure sums)
#pragma unroll
    for (int off = 1; off < 8; off <<= 1) {
#pragma unroll
        for (int hd = 0; hd < HH; hd++) {
            l[hd]  += __shfl_xor(l[hd], off, 64);
            Sx[hd] += __shfl_xor(Sx[hd], off, 64);
            Sy[hd] += __shfl_xor(Sy[hd], off, 64);
        }
#pragma unroll
        for (int j = 0; j < DD; j++) accv[j] += __shfl_xor(accv[j], off, 64);
    }

    if (g == 0) {
        float* ho = hout + (size_t)n * DS;
#pragma unroll
        for (int hd = 0; hd < HH; hd++) {
            float inv = 1.0f / (l[hd] + 1e-16f);
#pragma unroll
            for (int c = 0; c < CC; c++) {
                int j = hd * CC + c;
                ho[j] += (accv[j] + Sx[hd] * sWe[j] + Sy[hd] * sWe[DD + j]) * inv;
            }
        }
    }
}

// ---------------- output head ----------------
__global__ void k_head(const float* __restrict__ h, const float* __restrict__ Wo,
                       const float* __restrict__ bo, float* __restrict__ out) {
    __shared__ float sW[DD];
    __shared__ float sb0;
    if (threadIdx.x < DD) sW[threadIdx.x] = Wo[threadIdx.x];
    if (threadIdx.x == 0) sb0 = bo[0];
    __syncthreads();
    int n = blockIdx.x * blockDim.x + threadIdx.x;
    if (n >= NN) return;
    float acc = sb0;
    const float* hr = h + (size_t)n * DS;
#pragma unroll
    for (int i = 0; i < DD; i++) acc += hr[i] * sW[i];
    out[n] = 1.0f / (1.0f + __expf(-acc));
}

extern "C" void kernel_launch(void* const* d_in, const int* in_sizes, int n_in,
                              void* d_out, int out_size, void* d_ws, size_t ws_size,
                              hipStream_t stream) {
    const float* x     = (const float*)d_in[0];
    const int*   ei    = (const int*)d_in[1];     // [2,E]: src=[0..E), dst=[E..2E)
    const float* ea    = (const float*)d_in[2];   // [E,2]
    const float* Wi    = (const float*)d_in[3];
    const float* bi    = (const float*)d_in[4];
    const float* Wq    = (const float*)d_in[5];
    const float* bq    = (const float*)d_in[6];
    const float* Wk    = (const float*)d_in[7];
    const float* bk    = (const float*)d_in[8];
    const float* Wv    = (const float*)d_in[9];
    const float* bv    = (const float*)d_in[10];
    const float* We    = (const float*)d_in[11];
    const float* Wskip = (const float*)d_in[12];
    const float* bskip = (const float*)d_in[13];
    const float* Wo    = (const float*)d_in[14];
    const float* bo    = (const float*)d_in[15];
    float* out = (float*)d_out;
    (void)in_sizes; (void)n_in; (void)out_size; (void)ws_size;

    char* wsb = (char*)d_ws;
    size_t off = 0;
    auto alloc = [&](size_t bytes) {
        void* p = wsb + off;
        off += (bytes + 127) & ~(size_t)127;
        return p;
    };
    uint2* csr    = (uint2*)alloc((size_t)NE * sizeof(uint2));               // 12.8 MB
    __hip_bfloat16* kvrec = (__hip_bfloat16*)alloc((size_t)NN * KVS * 2);    // 12.8 MB
    float* hA     = (float*)alloc((size_t)NN * DS * sizeof(float));
    float* hB     = (float*)alloc((size_t)NN * DS * sizeof(float));
    float* q      = (float*)alloc((size_t)NN * DS * sizeof(float));
    int*   deg    = (int*)alloc((size_t)NN * sizeof(int));
    int*   excl   = (int*)alloc((size_t)NN * sizeof(int));
    int*   bsum   = (int*)alloc((size_t)NB1 * sizeof(int));
    int*   rowptr = (int*)alloc((size_t)(NN + 1) * sizeof(int));
    int*   cur    = (int*)alloc((size_t)NN * sizeof(int));

    dim3 blk(256);
    int gN  = (NN + 255) / 256;         // 391
    int gH  = (NE / 4 + 255) / 256;     // 1563
    int gND = (NN * DD + 255) / 256;    // 9766
    int gF  = NN / 32;                  // 3125 (exact)
    int gS  = NCH * NBUCK;              // 6400

    // CSR build (every call — ws is re-poisoned)
    k_zero_deg<<<gN, blk, 0, stream>>>(deg);
    k_hist<<<gH, blk, 0, stream>>>(ei, deg);
    k_scan1<<<gN, blk, 0, stream>>>(deg, excl, bsum);
    k_scan2<<<1, dim3(512), 0, stream>>>(bsum);
    k_scan3<<<gN, blk, 0, stream>>>(excl, bsum, rowptr, cur);
    k_scatter<<<gS, blk, 0, stream>>>(ei, ea, cur, csr);

    k_input_proj<<<gND, blk, 0, stream>>>(x, Wi, bi, hA);

    float* hc = hA;
    float* hn = hB;
    for (int l = 0; l < 3; l++) {
        k_qkv_skip<<<gND, blk, 0, stream>>>(hc,
                                            Wq + (size_t)l * DD * DD, bq + (size_t)l * DD,
                                            Wk + (size_t)l * DD * DD, bk + (size_t)l * DD,
                                            Wv + (size_t)l * DD * DD, bv + (size_t)l * DD,
                                            Wskip + (size_t)l * DD * DD, bskip + (size_t)l * DD,
                                            q, kvrec, hn);
        k_edge_fused<<<gF, blk, 0, stream>>>(rowptr, csr,
                                             We + (size_t)l * EDGE_DIM * DD,
                                             q, kvrec, hn);
        float* t = hc; hc = hn; hn = t;
    }
    k_head<<<gN, blk, 0, stream>>>(hc, Wo, bo, out);
}

// Round 5
// 430.468 us; speedup vs baseline: 19.7193x; 1.1020x over previous
//
#include <hip/hip_runtime.h>
#include <hip/hip_bf16.h>
#include <math.h>

#define NN 100000      // nodes
#define NE 1600000     // edges
#define IN_DIM 6
#define EDGE_DIM 2
#define HH 5           // heads
#define CC 5           // channels/head
#define DD 25          // hidden = HH*CC
#define DS 32          // padded fp32 row stride (128B rows)
#define QS 32          // bf16 q row stride in shorts (64 B rows)
#define KVS 64         // bf16 kv record stride in shorts: k@0..24, v@32..56 -> 128 B
#define INV_SQRT_C 0.4472135954999579f
#define SCAN_B 256
#define NB1 ((NN + SCAN_B - 1) / SCAN_B)   // 391
#define NBUK 200       // coarse dst buckets
#define BUKW 500       // nodes per bucket (200*500 = 100000 exact)
#define CAP 10000      // slab capacity per bucket (avg 8000, Poisson-safe)
#define CH 8000        // edges per k_part block (200*8000 = 1.6M exact)

__device__ __forceinline__ unsigned int f2bf(float f) {   // fp32 -> bf16 bits (RNE)
    unsigned int u = __float_as_uint(f);
    return (u + 0x7fffu + ((u >> 16) & 1u)) >> 16;
}
__device__ __forceinline__ float bflo(unsigned int u) { return __uint_as_float(u << 16); }
__device__ __forceinline__ float bfhi(unsigned int u) { return __uint_as_float(u & 0xffff0000u); }

// ---------------- init: deg=0, bucket cursors = slab bases ----------------
__global__ void k_init(int* __restrict__ deg, int* __restrict__ cursor) {
    int i = blockIdx.x * 256 + threadIdx.x;
    if (i < NN) deg[i] = 0;
    if (i < NBUK) cursor[i] = i * CAP;
}

// ---------------- phase 1: bucket-partition edges + global deg hist ----------------
// 200 blocks x 8000 edges. Records per (block,bucket) are contiguous in the slab:
// writes from one block/XCD -> line write-amp ~1.2x instead of ~8x.
__global__ __launch_bounds__(256) void k_part(const int* __restrict__ ei,
                                              const float* __restrict__ ea,
                                              int* __restrict__ deg,
                                              int* __restrict__ cursor,
                                              uint2* __restrict__ slab) {
    __shared__ int sdst[CH];        // 32 KB
    __shared__ int scnt[NBUK];
    __shared__ int sbase[NBUK];
    __shared__ int swp[NBUK];
    int base = blockIdx.x * CH;
    for (int i = threadIdx.x; i < NBUK; i += 256) scnt[i] = 0;
    __syncthreads();
    for (int i = threadIdx.x; i < CH; i += 256) {
        int dst = ei[NE + base + i];
        sdst[i] = dst;
        atomicAdd(&deg[dst], 1);
        atomicAdd(&scnt[dst / BUKW], 1);
    }
    __syncthreads();
    for (int i = threadIdx.x; i < NBUK; i += 256) {
        sbase[i] = atomicAdd(&cursor[i], scnt[i]);
        swp[i] = 0;
    }
    __syncthreads();
    for (int i = threadIdx.x; i < CH; i += 256) {
        int dst = sdst[i];
        int b = dst / BUKW;
        int src = ei[base + i];
        float2 eav = ((const float2*)ea)[base + i];
        int p = sbase[b] + atomicAdd(&swp[b], 1);
        uint2 r;
        r.x = (unsigned)src | ((unsigned)(dst - b * BUKW) << 17);  // src:17b, dstLocal:9b
        r.y = f2bf(eav.x) | (f2bf(eav.y) << 16);
        slab[p] = r;
    }
}

// ---------------- rowptr scan ----------------
__global__ void k_scan1(const int* __restrict__ deg, int* __restrict__ excl,
                        int* __restrict__ bsum) {
    __shared__ int s[SCAN_B];
    int i = blockIdx.x * SCAN_B + threadIdx.x;
    int v = (i < NN) ? deg[i] : 0;
    s[threadIdx.x] = v;
    __syncthreads();
    for (int off = 1; off < SCAN_B; off <<= 1) {
        int t = (threadIdx.x >= off) ? s[threadIdx.x - off] : 0;
        __syncthreads();
        s[threadIdx.x] += t;
        __syncthreads();
    }
    if (i < NN) excl[i] = s[threadIdx.x] - v;
    if (threadIdx.x == SCAN_B - 1) bsum[blockIdx.x] = s[SCAN_B - 1];
}

__global__ void k_scan2(int* __restrict__ bsum) {   // single block of 512
    __shared__ int s[512];
    int t = threadIdx.x;
    int v = (t < NB1) ? bsum[t] : 0;
    s[t] = v;
    __syncthreads();
    for (int off = 1; off < 512; off <<= 1) {
        int u = (t >= off) ? s[t - off] : 0;
        __syncthreads();
        s[t] += u;
        __syncthreads();
    }
    if (t < NB1) bsum[t] = s[t] - v;   // exclusive block offsets
}

__global__ void k_scan3(const int* __restrict__ excl, const int* __restrict__ bsum,
                        int* __restrict__ rowptr) {
    int i = blockIdx.x * 256 + threadIdx.x;
    if (i < NN) rowptr[i] = excl[i] + bsum[i / SCAN_B];
    if (i == 0) rowptr[NN] = NE;
}

// ---------------- phase 2: place records into CSR (one block per bucket) ----------------
// Each bucket's 64-KB CSR region is written by exactly one block/XCD -> writeback once.
__global__ __launch_bounds__(256) void k_place(const int* __restrict__ cursor,
                                               const uint2* __restrict__ slab,
                                               const int* __restrict__ rowptr,
                                               uint2* __restrict__ csr) {
    __shared__ int cur[BUKW];
    int b = blockIdx.x;
    int node0 = b * BUKW;
    for (int i = threadIdx.x; i < BUKW; i += 256) cur[i] = rowptr[node0 + i];
    __syncthreads();
    int begin = b * CAP;
    int cnt = cursor[b] - begin;
    for (int i = threadIdx.x; i < cnt; i += 256) {
        uint2 r = slab[begin + i];
        int dl = (int)(r.x >> 17);
        int p = atomicAdd(&cur[dl], 1);
        uint2 o;
        o.x = r.x & 0x1FFFFu;
        o.y = r.y;
        csr[p] = o;
    }
}

// ---------------- input projection ----------------
__global__ void k_input_proj(const float* __restrict__ x, const float* __restrict__ Wi,
                             const float* __restrict__ bi, float* __restrict__ h) {
    __shared__ float sW[IN_DIM * DD];
    __shared__ float sb[DD];
    int t = threadIdx.x;
    if (t < IN_DIM * DD) sW[t] = Wi[t];
    if (t < DD) sb[t] = bi[t];
    __syncthreads();
    int tid = blockIdx.x * blockDim.x + t;
    int n = tid / DD, d = tid - n * DD;
    if (n >= NN) return;
    float acc = sb[d];
    const float* xr = x + n * IN_DIM;
#pragma unroll
    for (int i = 0; i < IN_DIM; i++) acc += xr[i] * sW[i * DD + d];
    h[n * DS + d] = acc;
}

// ------- per-layer node pass: q (pre-scaled bf16), kv (packed bf16), skip -------
__global__ void k_qkv_skip(const float* __restrict__ h,
                           const float* __restrict__ Wq, const float* __restrict__ bq,
                           const float* __restrict__ Wk, const float* __restrict__ bk,
                           const float* __restrict__ Wv, const float* __restrict__ bv,
                           const float* __restrict__ Ws, const float* __restrict__ bs,
                           __hip_bfloat16* __restrict__ q, __hip_bfloat16* __restrict__ kv,
                           float* __restrict__ hout) {
    __shared__ float sWq[DD * DD], sWk[DD * DD], sWv[DD * DD], sWs[DD * DD];
    __shared__ float sb[4 * DD];
    for (int i = threadIdx.x; i < DD * DD; i += blockDim.x) {
        sWq[i] = Wq[i]; sWk[i] = Wk[i]; sWv[i] = Wv[i]; sWs[i] = Ws[i];
    }
    if (threadIdx.x < DD) {
        sb[threadIdx.x]          = bq[threadIdx.x];
        sb[DD + threadIdx.x]     = bk[threadIdx.x];
        sb[2 * DD + threadIdx.x] = bv[threadIdx.x];
        sb[3 * DD + threadIdx.x] = bs[threadIdx.x];
    }
    __syncthreads();
    int tid = blockIdx.x * blockDim.x + threadIdx.x;
    int n = tid / DD, d = tid - n * DD;
    if (n >= NN) return;
    float aq = sb[d], ak = sb[DD + d], av = sb[2 * DD + d], asv = sb[3 * DD + d];
    const float* hr = h + (size_t)n * DS;
#pragma unroll
    for (int i = 0; i < DD; i++) {
        float hv = hr[i];
        aq  += hv * sWq[i * DD + d];
        ak  += hv * sWk[i * DD + d];
        av  += hv * sWv[i * DD + d];
        asv += hv * sWs[i * DD + d];
    }
    q[(size_t)n * QS + d] = __float2bfloat16(aq * INV_SQRT_C);  // fold 1/sqrt(C)
    kv[(size_t)n * KVS + d]      = __float2bfloat16(ak);
    kv[(size_t)n * KVS + 32 + d] = __float2bfloat16(av);
    hout[(size_t)n * DS + d] = asv;
}

// ---------------- fused edge pass: plain-exp softmax + aggregate, no atomics ----------------
// 8 lanes per destination node; 32 nodes per 256-thread block. NN = 3125*32 exactly.
__global__ __launch_bounds__(256) void k_edge_fused(
    const int* __restrict__ rowptr, const uint2* __restrict__ csr,
    const float* __restrict__ We, const __hip_bfloat16* __restrict__ q,
    const __hip_bfloat16* __restrict__ kv, float* __restrict__ hout) {
    __shared__ float sWe[EDGE_DIM * DD];
    if (threadIdx.x < EDGE_DIM * DD) sWe[threadIdx.x] = We[threadIdx.x];
    __syncthreads();
    int n = blockIdx.x * 32 + (threadIdx.x >> 3);
    int g = threadIdx.x & 7;
    if (n >= NN) return;
    int beg = rowptr[n], end = rowptr[n + 1];

    float qa[26];
    {
        const uint4* qr = (const uint4*)(q + (size_t)n * QS);
        uint4 q0 = qr[0], q1 = qr[1], q2 = qr[2], q3 = qr[3];
        qa[0]=bflo(q0.x); qa[1]=bfhi(q0.x); qa[2]=bflo(q0.y); qa[3]=bfhi(q0.y);
        qa[4]=bflo(q0.z); qa[5]=bfhi(q0.z); qa[6]=bflo(q0.w); qa[7]=bfhi(q0.w);
        qa[8]=bflo(q1.x); qa[9]=bfhi(q1.x); qa[10]=bflo(q1.y); qa[11]=bfhi(q1.y);
        qa[12]=bflo(q1.z); qa[13]=bfhi(q1.z); qa[14]=bflo(q1.w); qa[15]=bfhi(q1.w);
        qa[16]=bflo(q2.x); qa[17]=bfhi(q2.x); qa[18]=bflo(q2.y); qa[19]=bfhi(q2.y);
        qa[20]=bflo(q2.z); qa[21]=bfhi(q2.z); qa[22]=bflo(q2.w); qa[23]=bfhi(q2.w);
        qa[24]=bflo(q3.x);
    }
    // per-node q . We (q already carries 1/sqrt(C))
    float qwx[HH], qwy[HH];
#pragma unroll
    for (int hd = 0; hd < HH; hd++) {
        float sx = 0.0f, sy = 0.0f;
#pragma unroll
        for (int c = 0; c < CC; c++) {
            int j = hd * CC + c;
            sx += qa[j] * sWe[j];
            sy += qa[j] * sWe[DD + j];
        }
        qwx[hd] = sx; qwy[hd] = sy;
    }

    float l[HH], Sx[HH], Sy[HH], accv[DD];
#pragma unroll
    for (int hd = 0; hd < HH; hd++) { l[hd] = 0.0f; Sx[hd] = 0.0f; Sy[hd] = 0.0f; }
#pragma unroll
    for (int j = 0; j < DD; j++) accv[j] = 0.0f;

    for (int p = beg + g; p < end; p += 8) {
        uint2 rec = csr[p];
        int src = (int)rec.x;
        float eax = bflo(rec.y), eay = bfhi(rec.y);

        // one 128-B line: k bf16[25] @ shorts 0..24, v bf16[25] @ shorts 32..56
        const uint4* kr = (const uint4*)(kv + (size_t)src * KVS);
        uint4 r0 = kr[0], r1 = kr[1], r2 = kr[2], r3 = kr[3];   // k
        uint4 r4 = kr[4], r5 = kr[5], r6 = kr[6], r7 = kr[7];   // v

        float kb[26];
        kb[0]=bflo(r0.x); kb[1]=bfhi(r0.x); kb[2]=bflo(r0.y); kb[3]=bfhi(r0.y);
        kb[4]=bflo(r0.z); kb[5]=bfhi(r0.z); kb[6]=bflo(r0.w); kb[7]=bfhi(r0.w);
        kb[8]=bflo(r1.x); kb[9]=bfhi(r1.x); kb[10]=bflo(r1.y); kb[11]=bfhi(r1.y);
        kb[12]=bflo(r1.z); kb[13]=bfhi(r1.z); kb[14]=bflo(r1.w); kb[15]=bfhi(r1.w);
        kb[16]=bflo(r2.x); kb[17]=bfhi(r2.x); kb[18]=bflo(r2.y); kb[19]=bfhi(r2.y);
        kb[20]=bflo(r2.z); kb[21]=bfhi(r2.z); kb[22]=bflo(r2.w); kb[23]=bfhi(r2.w);
        kb[24]=bflo(r3.x);

        float al[HH];
#pragma unroll
        for (int hd = 0; hd < HH; hd++) {
            float s = eax * qwx[hd] + eay * qwy[hd];
#pragma unroll
            for (int c = 0; c < CC; c++) {
                int j = hd * CC + c;
                s += qa[j] * kb[j];
            }
            al[hd] = __expf(s);
        }

        float vb[26];
        vb[0]=bflo(r4.x); vb[1]=bfhi(r4.x); vb[2]=bflo(r4.y); vb[3]=bfhi(r4.y);
        vb[4]=bflo(r4.z); vb[5]=bfhi(r4.z); vb[6]=bflo(r4.w); vb[7]=bfhi(r4.w);
        vb[8]=bflo(r5.x); vb[9]=bfhi(r5.x); vb[10]=bflo(r5.y); vb[11]=bfhi(r5.y);
        vb[12]=bflo(r5.z); vb[13]=bfhi(r5.z); vb[14]=bflo(r5.w); vb[15]=bfhi(r5.w);
        vb[16]=bflo(r6.x); vb[17]=bfhi(r6.x); vb[18]=bflo(r6.y); vb[19]=bfhi(r6.y);
        vb[20]=bflo(r6.z); vb[21]=bfhi(r6.z); vb[22]=bflo(r6.w); vb[23]=bfhi(r6.w);
        vb[24]=bflo(r7.x);

#pragma unroll
        for (int hd = 0; hd < HH; hd++) {
            float cf = al[hd];
            l[hd]  += cf;
            Sx[hd] += cf * eax;
            Sy[hd] += cf * eay;
#pragma unroll
            for (int c = 0; c < CC; c++) {
                int j = hd * CC + c;
                accv[j] += cf * vb[j];
            }
        }
    }

    // merge 8 lanes per node (pure sums)
#pragma unroll
    for (int off = 1; off < 8; off <<= 1) {
#pragma unroll
        for (int hd = 0; hd < HH; hd++) {
            l[hd]  += __shfl_xor(l[hd], off, 64);
            Sx[hd] += __shfl_xor(Sx[hd], off, 64);
            Sy[hd] += __shfl_xor(Sy[hd], off, 64);
        }
#pragma unroll
        for (int j = 0; j < DD; j++) accv[j] += __shfl_xor(accv[j], off, 64);
    }

    if (g == 0) {
        float* ho = hout + (size_t)n * DS;
#pragma unroll
        for (int hd = 0; hd < HH; hd++) {
            float inv = 1.0f / (l[hd] + 1e-16f);
#pragma unroll
            for (int c = 0; c < CC; c++) {
                int j = hd * CC + c;
                ho[j] += (accv[j] + Sx[hd] * sWe[j] + Sy[hd] * sWe[DD + j]) * inv;
            }
        }
    }
}

// ---------------- output head ----------------
__global__ void k_head(const float* __restrict__ h, const float* __restrict__ Wo,
                       const float* __restrict__ bo, float* __restrict__ out) {
    __shared__ float sW[DD];
    __shared__ float sb0;
    if (threadIdx.x < DD) sW[threadIdx.x] = Wo[threadIdx.x];
    if (threadIdx.x == 0) sb0 = bo[0];
    __syncthreads();
    int n = blockIdx.x * blockDim.x + threadIdx.x;
    if (n >= NN) return;
    float acc = sb0;
    const float* hr = h + (size_t)n * DS;
#pragma unroll
    for (int i = 0; i < DD; i++) acc += hr[i] * sW[i];
    out[n] = 1.0f / (1.0f + __expf(-acc));
}

extern "C" void kernel_launch(void* const* d_in, const int* in_sizes, int n_in,
                              void* d_out, int out_size, void* d_ws, size_t ws_size,
                              hipStream_t stream) {
    const float* x     = (const float*)d_in[0];
    const int*   ei    = (const int*)d_in[1];     // [2,E]: src=[0..E), dst=[E..2E)
    const float* ea    = (const float*)d_in[2];   // [E,2]
    const float* Wi    = (const float*)d_in[3];
    const float* bi    = (const float*)d_in[4];
    const float* Wq    = (const float*)d_in[5];
    const float* bq    = (const float*)d_in[6];
    const float* Wk    = (const float*)d_in[7];
    const float* bk    = (const float*)d_in[8];
    const float* Wv    = (const float*)d_in[9];
    const float* bv    = (const float*)d_in[10];
    const float* We    = (const float*)d_in[11];
    const float* Wskip = (const float*)d_in[12];
    const float* bskip = (const float*)d_in[13];
    const float* Wo    = (const float*)d_in[14];
    const float* bo    = (const float*)d_in[15];
    float* out = (float*)d_out;
    (void)in_sizes; (void)n_in; (void)out_size; (void)ws_size;

    char* wsb = (char*)d_ws;
    size_t off = 0;
    auto alloc = [&](size_t bytes) {
        void* p = wsb + off;
        off += (bytes + 127) & ~(size_t)127;
        return p;
    };
    uint2* slab   = (uint2*)alloc((size_t)NBUK * CAP * sizeof(uint2));       // 16 MB
    uint2* csr    = (uint2*)alloc((size_t)NE * sizeof(uint2));               // 12.8 MB
    __hip_bfloat16* kvrec = (__hip_bfloat16*)alloc((size_t)NN * KVS * 2);    // 12.8 MB
    __hip_bfloat16* qrec  = (__hip_bfloat16*)alloc((size_t)NN * QS * 2);     // 6.4 MB
    float* hA     = (float*)alloc((size_t)NN * DS * sizeof(float));
    float* hB     = (float*)alloc((size_t)NN * DS * sizeof(float));
    int*   deg    = (int*)alloc((size_t)NN * sizeof(int));
    int*   excl   = (int*)alloc((size_t)NN * sizeof(int));
    int*   bsum   = (int*)alloc((size_t)NB1 * sizeof(int));
    int*   rowptr = (int*)alloc((size_t)(NN + 1) * sizeof(int));
    int*   cursor = (int*)alloc((size_t)NBUK * sizeof(int));

    dim3 blk(256);
    int gN  = (NN + 255) / 256;         // 391
    int gND = (NN * DD + 255) / 256;    // 9766
    int gF  = NN / 32;                  // 3125 (exact)

    // CSR build (every call — ws is re-poisoned)
    k_init<<<gN, blk, 0, stream>>>(deg, cursor);
    k_part<<<NBUK, blk, 0, stream>>>(ei, ea, deg, cursor, slab);
    k_scan1<<<gN, blk, 0, stream>>>(deg, excl, bsum);
    k_scan2<<<1, dim3(512), 0, stream>>>(bsum);
    k_scan3<<<gN, blk, 0, stream>>>(excl, bsum, rowptr);
    k_place<<<NBUK, blk, 0, stream>>>(cursor, slab, rowptr, csr);

    k_input_proj<<<gND, blk, 0, stream>>>(x, Wi, bi, hA);

    float* hc = hA;
    float* hn = hB;
    for (int l = 0; l < 3; l++) {
        k_qkv_skip<<<gND, blk, 0, stream>>>(hc,
                                            Wq + (size_t)l * DD * DD, bq + (size_t)l * DD,
                                            Wk + (size_t)l * DD * DD, bk + (size_t)l * DD,
                                            Wv + (size_t)l * DD * DD, bv + (size_t)l * DD,
                                            Wskip + (size_t)l * DD * DD, bskip + (size_t)l * DD,
                                            qrec, kvrec, hn);
        k_edge_fused<<<gF, blk, 0, stream>>>(rowptr, csr,
                                             We + (size_t)l * EDGE_DIM * DD,
                                             qrec, kvrec, hn);
        float* t = hc; hc = hn; hn = t;
    }
    k_head<<<gN, blk, 0, stream>>>(hc, Wo, bo, out);
}

// Round 6
// 380.001 us; speedup vs baseline: 22.3381x; 1.1328x over previous
//
#include <hip/hip_runtime.h>
#include <hip/hip_bf16.h>
#include <math.h>

#define NN 100000      // nodes
#define NE 1600000     // edges
#define IN_DIM 6
#define EDGE_DIM 2
#define HH 5           // heads
#define CC 5           // channels/head
#define DD 25          // hidden = HH*CC
#define DS 32          // padded fp32 row stride (128B rows)
#define QS 32          // bf16 q row stride in shorts (64 B rows)
#define KVS 64         // bf16 kv record stride in shorts: k@0..24, v@32..56 -> 128 B
#define INV_SQRT_C 0.4472135954999579f
#define NBUK 200       // coarse dst buckets
#define BUKW 500       // nodes per bucket (200*500 = 100000 exact)
#define CAP 10000      // slab capacity per bucket (avg 8000, safe)
#define KPB 800        // k_part blocks
#define CH (NE / KPB)  // 2000 edges per k_part block

__device__ __forceinline__ unsigned int f2bf(float f) {   // fp32 -> bf16 bits (RNE)
    unsigned int u = __float_as_uint(f);
    return (u + 0x7fffu + ((u >> 16) & 1u)) >> 16;
}
__device__ __forceinline__ float bflo(unsigned int u) { return __uint_as_float(u << 16); }
__device__ __forceinline__ float bfhi(unsigned int u) { return __uint_as_float(u & 0xffff0000u); }

// ---------------- init: bucket cursors = slab bases ----------------
__global__ void k_init(int* __restrict__ cursor) {
    int i = threadIdx.x;
    if (i < NBUK) cursor[i] = i * CAP;
}

// ---------------- phase 1: bucket-partition edges (no global histogram) ----------------
// 800 blocks x 2000 edges. Records per (block,bucket) contiguous in the slab.
__global__ __launch_bounds__(256) void k_part(const int* __restrict__ ei,
                                              const float* __restrict__ ea,
                                              int* __restrict__ cursor,
                                              uint2* __restrict__ slab) {
    __shared__ int sdst[CH];        // 8 KB
    __shared__ int scnt[NBUK];
    __shared__ int sbase[NBUK];
    __shared__ int swp[NBUK];
    int base = blockIdx.x * CH;
    for (int i = threadIdx.x; i < NBUK; i += 256) scnt[i] = 0;
    __syncthreads();
    for (int i = threadIdx.x; i < CH; i += 256) {
        int dst = ei[NE + base + i];
        sdst[i] = dst;
        atomicAdd(&scnt[dst / BUKW], 1);
    }
    __syncthreads();
    for (int i = threadIdx.x; i < NBUK; i += 256) {
        sbase[i] = atomicAdd(&cursor[i], scnt[i]);
        swp[i] = 0;
    }
    __syncthreads();
    for (int i = threadIdx.x; i < CH; i += 256) {
        int dst = sdst[i];
        int b = dst / BUKW;
        int src = ei[base + i];
        float2 eav = ((const float2*)ea)[base + i];
        int p = sbase[b] + atomicAdd(&swp[b], 1);
        uint2 r;
        r.x = (unsigned)src | ((unsigned)(dst - b * BUKW) << 17);  // src:17b, dstLocal:9b
        r.y = f2bf(eav.x) | (f2bf(eav.y) << 16);
        slab[p] = r;
    }
}

// ---------------- bucket-base scan (1 block) ----------------
__global__ void k_scanB(const int* __restrict__ cursor, int* __restrict__ bucketOff,
                        int* __restrict__ rowptr) {
    __shared__ int s[256];
    int t = threadIdx.x;
    int v = (t < NBUK) ? (cursor[t] - t * CAP) : 0;
    s[t] = v;
    __syncthreads();
    for (int off = 1; off < 256; off <<= 1) {
        int u = (t >= off) ? s[t - off] : 0;
        __syncthreads();
        s[t] += u;
        __syncthreads();
    }
    if (t < NBUK) bucketOff[t] = s[t] - v;   // exclusive
    if (t == 0) rowptr[NN] = NE;
}

// ---------------- phase 2: per-bucket hist + scan + rowptr + place ----------------
// One block per bucket; bucket's CSR region written by exactly one block/XCD.
__global__ __launch_bounds__(512) void k_place(const int* __restrict__ cursor,
                                               const uint2* __restrict__ slab,
                                               const int* __restrict__ bucketOff,
                                               int* __restrict__ rowptr,
                                               uint2* __restrict__ csr) {
    __shared__ int hist[BUKW];
    __shared__ int cur[BUKW];
    __shared__ int s[512];
    int b = blockIdx.x;
    int node0 = b * BUKW;
    int begin = b * CAP;
    int cnt = cursor[b] - begin;
    int bOff = bucketOff[b];
    for (int i = threadIdx.x; i < BUKW; i += 512) hist[i] = 0;
    __syncthreads();
    for (int i = threadIdx.x; i < cnt; i += 512) {
        uint2 r = slab[begin + i];
        atomicAdd(&hist[r.x >> 17], 1);
    }
    __syncthreads();
    // exclusive scan of hist[0..BUKW) with 512 threads
    int t = threadIdx.x;
    int v = (t < BUKW) ? hist[t] : 0;
    s[t] = v;
    __syncthreads();
    for (int off = 1; off < 512; off <<= 1) {
        int u = (t >= off) ? s[t - off] : 0;
        __syncthreads();
        s[t] += u;
        __syncthreads();
    }
    if (t < BUKW) {
        int o = bOff + s[t] - v;
        rowptr[node0 + t] = o;
        cur[t] = o;
    }
    __syncthreads();
    for (int i = threadIdx.x; i < cnt; i += 512) {
        uint2 r = slab[begin + i];         // L2 hit (just streamed)
        int dl = (int)(r.x >> 17);
        int p = atomicAdd(&cur[dl], 1);
        uint2 o;
        o.x = r.x & 0x1FFFFu;
        o.y = r.y;
        csr[p] = o;
    }
}

// ---------------- input projection ----------------
__global__ void k_input_proj(const float* __restrict__ x, const float* __restrict__ Wi,
                             const float* __restrict__ bi, float* __restrict__ h) {
    __shared__ float sW[IN_DIM * DD];
    __shared__ float sb[DD];
    int t = threadIdx.x;
    if (t < IN_DIM * DD) sW[t] = Wi[t];
    if (t < DD) sb[t] = bi[t];
    __syncthreads();
    int tid = blockIdx.x * blockDim.x + t;
    int n = tid / DD, d = tid - n * DD;
    if (n >= NN) return;
    float acc = sb[d];
    const float* xr = x + n * IN_DIM;
#pragma unroll
    for (int i = 0; i < IN_DIM; i++) acc += xr[i] * sW[i * DD + d];
    h[n * DS + d] = acc;
}

// ------- per-layer node pass: q (pre-scaled bf16), kv (packed bf16), skip -------
__global__ void k_qkv_skip(const float* __restrict__ h,
                           const float* __restrict__ Wq, const float* __restrict__ bq,
                           const float* __restrict__ Wk, const float* __restrict__ bk,
                           const float* __restrict__ Wv, const float* __restrict__ bv,
                           const float* __restrict__ Ws, const float* __restrict__ bs,
                           __hip_bfloat16* __restrict__ q, __hip_bfloat16* __restrict__ kv,
                           float* __restrict__ hout) {
    __shared__ float sWq[DD * DD], sWk[DD * DD], sWv[DD * DD], sWs[DD * DD];
    __shared__ float sb[4 * DD];
    for (int i = threadIdx.x; i < DD * DD; i += blockDim.x) {
        sWq[i] = Wq[i]; sWk[i] = Wk[i]; sWv[i] = Wv[i]; sWs[i] = Ws[i];
    }
    if (threadIdx.x < DD) {
        sb[threadIdx.x]          = bq[threadIdx.x];
        sb[DD + threadIdx.x]     = bk[threadIdx.x];
        sb[2 * DD + threadIdx.x] = bv[threadIdx.x];
        sb[3 * DD + threadIdx.x] = bs[threadIdx.x];
    }
    __syncthreads();
    int tid = blockIdx.x * blockDim.x + threadIdx.x;
    int n = tid / DD, d = tid - n * DD;
    if (n >= NN) return;
    float aq = sb[d], ak = sb[DD + d], av = sb[2 * DD + d], asv = sb[3 * DD + d];
    const float* hr = h + (size_t)n * DS;
#pragma unroll
    for (int i = 0; i < DD; i++) {
        float hv = hr[i];
        aq  += hv * sWq[i * DD + d];
        ak  += hv * sWk[i * DD + d];
        av  += hv * sWv[i * DD + d];
        asv += hv * sWs[i * DD + d];
    }
    q[(size_t)n * QS + d] = __float2bfloat16(aq * INV_SQRT_C);  // fold 1/sqrt(C)
    kv[(size_t)n * KVS + d]      = __float2bfloat16(ak);
    kv[(size_t)n * KVS + 32 + d] = __float2bfloat16(av);
    hout[(size_t)n * DS + d] = asv;
}

// ---------------- fused edge pass: plain-exp softmax + aggregate, no atomics ----------------
// 8 lanes per destination node; 32 nodes per 256-thread block. NN = 3125*32 exactly.
__global__ __launch_bounds__(256) void k_edge_fused(
    const int* __restrict__ rowptr, const uint2* __restrict__ csr,
    const float* __restrict__ We, const __hip_bfloat16* __restrict__ q,
    const __hip_bfloat16* __restrict__ kv, float* __restrict__ hout) {
    __shared__ float sWe[EDGE_DIM * DD];
    if (threadIdx.x < EDGE_DIM * DD) sWe[threadIdx.x] = We[threadIdx.x];
    __syncthreads();
    int n = blockIdx.x * 32 + (threadIdx.x >> 3);
    int g = threadIdx.x & 7;
    if (n >= NN) return;
    int beg = rowptr[n], end = rowptr[n + 1];

    float qa[26];
    {
        const uint4* qr = (const uint4*)(q + (size_t)n * QS);
        uint4 q0 = qr[0], q1 = qr[1], q2 = qr[2], q3 = qr[3];
        qa[0]=bflo(q0.x); qa[1]=bfhi(q0.x); qa[2]=bflo(q0.y); qa[3]=bfhi(q0.y);
        qa[4]=bflo(q0.z); qa[5]=bfhi(q0.z); qa[6]=bflo(q0.w); qa[7]=bfhi(q0.w);
        qa[8]=bflo(q1.x); qa[9]=bfhi(q1.x); qa[10]=bflo(q1.y); qa[11]=bfhi(q1.y);
        qa[12]=bflo(q1.z); qa[13]=bfhi(q1.z); qa[14]=bflo(q1.w); qa[15]=bfhi(q1.w);
        qa[16]=bflo(q2.x); qa[17]=bfhi(q2.x); qa[18]=bflo(q2.y); qa[19]=bfhi(q2.y);
        qa[20]=bflo(q2.z); qa[21]=bfhi(q2.z); qa[22]=bflo(q2.w); qa[23]=bfhi(q2.w);
        qa[24]=bflo(q3.x);
    }
    // per-node q . We (q already carries 1/sqrt(C))
    float qwx[HH], qwy[HH];
#pragma unroll
    for (int hd = 0; hd < HH; hd++) {
        float sx = 0.0f, sy = 0.0f;
#pragma unroll
        for (int c = 0; c < CC; c++) {
            int j = hd * CC + c;
            sx += qa[j] * sWe[j];
            sy += qa[j] * sWe[DD + j];
        }
        qwx[hd] = sx; qwy[hd] = sy;
    }

    float l[HH], Sx[HH], Sy[HH], accv[DD];
#pragma unroll
    for (int hd = 0; hd < HH; hd++) { l[hd] = 0.0f; Sx[hd] = 0.0f; Sy[hd] = 0.0f; }
#pragma unroll
    for (int j = 0; j < DD; j++) accv[j] = 0.0f;

    for (int p = beg + g; p < end; p += 8) {
        uint2 rec = csr[p];
        int src = (int)rec.x;
        float eax = bflo(rec.y), eay = bfhi(rec.y);

        // one 128-B line: k bf16[25] @ shorts 0..24, v bf16[25] @ shorts 32..56
        const uint4* kr = (const uint4*)(kv + (size_t)src * KVS);
        uint4 r0 = kr[0], r1 = kr[1], r2 = kr[2], r3 = kr[3];   // k
        uint4 r4 = kr[4], r5 = kr[5], r6 = kr[6], r7 = kr[7];   // v

        float kb[26];
        kb[0]=bflo(r0.x); kb[1]=bfhi(r0.x); kb[2]=bflo(r0.y); kb[3]=bfhi(r0.y);
        kb[4]=bflo(r0.z); kb[5]=bfhi(r0.z); kb[6]=bflo(r0.w); kb[7]=bfhi(r0.w);
        kb[8]=bflo(r1.x); kb[9]=bfhi(r1.x); kb[10]=bflo(r1.y); kb[11]=bfhi(r1.y);
        kb[12]=bflo(r1.z); kb[13]=bfhi(r1.z); kb[14]=bflo(r1.w); kb[15]=bfhi(r1.w);
        kb[16]=bflo(r2.x); kb[17]=bfhi(r2.x); kb[18]=bflo(r2.y); kb[19]=bfhi(r2.y);
        kb[20]=bflo(r2.z); kb[21]=bfhi(r2.z); kb[22]=bflo(r2.w); kb[23]=bfhi(r2.w);
        kb[24]=bflo(r3.x);

        float al[HH];
#pragma unroll
        for (int hd = 0; hd < HH; hd++) {
            float s = eax * qwx[hd] + eay * qwy[hd];
#pragma unroll
            for (int c = 0; c < CC; c++) {
                int j = hd * CC + c;
                s += qa[j] * kb[j];
            }
            al[hd] = __expf(s);
        }

        float vb[26];
        vb[0]=bflo(r4.x); vb[1]=bfhi(r4.x); vb[2]=bflo(r4.y); vb[3]=bfhi(r4.y);
        vb[4]=bflo(r4.z); vb[5]=bfhi(r4.z); vb[6]=bflo(r4.w); vb[7]=bfhi(r4.w);
        vb[8]=bflo(r5.x); vb[9]=bfhi(r5.x); vb[10]=bflo(r5.y); vb[11]=bfhi(r5.y);
        vb[12]=bflo(r5.z); vb[13]=bfhi(r5.z); vb[14]=bflo(r5.w); vb[15]=bfhi(r5.w);
        vb[16]=bflo(r6.x); vb[17]=bfhi(r6.x); vb[18]=bflo(r6.y); vb[19]=bfhi(r6.y);
        vb[20]=bflo(r6.z); vb[21]=bfhi(r6.z); vb[22]=bflo(r6.w); vb[23]=bfhi(r6.w);
        vb[24]=bflo(r7.x);

#pragma unroll
        for (int hd = 0; hd < HH; hd++) {
            float cf = al[hd];
            l[hd]  += cf;
            Sx[hd] += cf * eax;
            Sy[hd] += cf * eay;
#pragma unroll
            for (int c = 0; c < CC; c++) {
                int j = hd * CC + c;
                accv[j] += cf * vb[j];
            }
        }
    }

    // merge 8 lanes per node (pure sums)
#pragma unroll
    for (int off = 1; off < 8; off <<= 1) {
#pragma unroll
        for (int hd = 0; hd < HH; hd++) {
            l[hd]  += __shfl_xor(l[hd], off, 64);
            Sx[hd] += __shfl_xor(Sx[hd], off, 64);
            Sy[hd] += __shfl_xor(Sy[hd], off, 64);
        }
#pragma unroll
        for (int j = 0; j < DD; j++) accv[j] += __shfl_xor(accv[j], off, 64);
    }

    if (g == 0) {
        float* ho = hout + (size_t)n * DS;
#pragma unroll
        for (int hd = 0; hd < HH; hd++) {
            float inv = 1.0f / (l[hd] + 1e-16f);
#pragma unroll
            for (int c = 0; c < CC; c++) {
                int j = hd * CC + c;
                ho[j] += (accv[j] + Sx[hd] * sWe[j] + Sy[hd] * sWe[DD + j]) * inv;
            }
        }
    }
}

// ---------------- output head ----------------
__global__ void k_head(const float* __restrict__ h, const float* __restrict__ Wo,
                       const float* __restrict__ bo, float* __restrict__ out) {
    __shared__ float sW[DD];
    __shared__ float sb0;
    if (threadIdx.x < DD) sW[threadIdx.x] = Wo[threadIdx.x];
    if (threadIdx.x == 0) sb0 = bo[0];
    __syncthreads();
    int n = blockIdx.x * blockDim.x + threadIdx.x;
    if (n >= NN) return;
    float acc = sb0;
    const float* hr = h + (size_t)n * DS;
#pragma unroll
    for (int i = 0; i < DD; i++) acc += hr[i] * sW[i];
    out[n] = 1.0f / (1.0f + __expf(-acc));
}

extern "C" void kernel_launch(void* const* d_in, const int* in_sizes, int n_in,
                              void* d_out, int out_size, void* d_ws, size_t ws_size,
                              hipStream_t stream) {
    const float* x     = (const float*)d_in[0];
    const int*   ei    = (const int*)d_in[1];     // [2,E]: src=[0..E), dst=[E..2E)
    const float* ea    = (const float*)d_in[2];   // [E,2]
    const float* Wi    = (const float*)d_in[3];
    const float* bi    = (const float*)d_in[4];
    const float* Wq    = (const float*)d_in[5];
    const float* bq    = (const float*)d_in[6];
    const float* Wk    = (const float*)d_in[7];
    const float* bk    = (const float*)d_in[8];
    const float* Wv    = (const float*)d_in[9];
    const float* bv    = (const float*)d_in[10];
    const float* We    = (const float*)d_in[11];
    const float* Wskip = (const float*)d_in[12];
    const float* bskip = (const float*)d_in[13];
    const float* Wo    = (const float*)d_in[14];
    const float* bo    = (const float*)d_in[15];
    float* out = (float*)d_out;
    (void)in_sizes; (void)n_in; (void)out_size; (void)ws_size;

    char* wsb = (char*)d_ws;
    size_t off = 0;
    auto alloc = [&](size_t bytes) {
        void* p = wsb + off;
        off += (bytes + 127) & ~(size_t)127;
        return p;
    };
    uint2* slab   = (uint2*)alloc((size_t)NBUK * CAP * sizeof(uint2));       // 16 MB
    uint2* csr    = (uint2*)alloc((size_t)NE * sizeof(uint2));               // 12.8 MB
    __hip_bfloat16* kvrec = (__hip_bfloat16*)alloc((size_t)NN * KVS * 2);    // 12.8 MB
    __hip_bfloat16* qrec  = (__hip_bfloat16*)alloc((size_t)NN * QS * 2);     // 6.4 MB
    float* hA     = (float*)alloc((size_t)NN * DS * sizeof(float));
    float* hB     = (float*)alloc((size_t)NN * DS * sizeof(float));
    int*   rowptr = (int*)alloc((size_t)(NN + 1) * sizeof(int));
    int*   cursor = (int*)alloc((size_t)NBUK * sizeof(int));
    int*   bucketOff = (int*)alloc((size_t)NBUK * sizeof(int));

    dim3 blk(256);
    int gN  = (NN + 255) / 256;         // 391
    int gND = (NN * DD + 255) / 256;    // 9766
    int gF  = NN / 32;                  // 3125 (exact)

    // CSR build (every call — ws is re-poisoned)
    k_init<<<1, blk, 0, stream>>>(cursor);
    k_part<<<KPB, blk, 0, stream>>>(ei, ea, cursor, slab);
    k_scanB<<<1, blk, 0, stream>>>(cursor, bucketOff, rowptr);
    k_place<<<NBUK, dim3(512), 0, stream>>>(cursor, slab, bucketOff, rowptr, csr);

    k_input_proj<<<gND, blk, 0, stream>>>(x, Wi, bi, hA);

    float* hc = hA;
    float* hn = hB;
    for (int l = 0; l < 3; l++) {
        k_qkv_skip<<<gND, blk, 0, stream>>>(hc,
                                            Wq + (size_t)l * DD * DD, bq + (size_t)l * DD,
                                            Wk + (size_t)l * DD * DD, bk + (size_t)l * DD,
                                            Wv + (size_t)l * DD * DD, bv + (size_t)l * DD,
                                            Wskip + (size_t)l * DD * DD, bskip + (size_t)l * DD,
                                            qrec, kvrec, hn);
        k_edge_fused<<<gF, blk, 0, stream>>>(rowptr, csr,
                                             We + (size_t)l * EDGE_DIM * DD,
                                             qrec, kvrec, hn);
        float* t = hc; hc = hn; hn = t;
    }
    k_head<<<gN, blk, 0, stream>>>(hc, Wo, bo, out);
}